// Round 11
// baseline (1111.890 us; speedup 1.0000x reference)
//
#include <hip/hip_runtime.h>
#include <hip/hip_bf16.h>
#include <stdint.h>

// GraphCON-GCN on MI355X.
// Algebra: with DT=ALPHA=GAMMA=1, Xs_{l+1} = relu(gcn+res); Y drops out.
// z = (A.Xs) Wc^T + (dinv^2-1) Xs Wc^T + Xs Wr^T + (b_c+b_r)  [self-term folded
// in-register]. State fp16, double-buffered (XsA/XsB). Edge record = 4B:
// (deg+1)<<18 | src; rsqrt(deg1) recomputed bit-exactly in the gather.
// r11: k_agg FUSED into k_layer — each block gathers U for its 128 rows into
// a swizzled 32KB LDS tile (kills the 51MB/layer U round-trip + 5 dispatches),
// then runs the two-pass fp16 MFMA (one 32KB weight matrix staged at a time).
// CSR build: simple deg + 3-phase scan + fill (line-granular scatter ~95us =
// accepted floor; r8 L2-windowing and r9 LDS-binning both failed).
// Decode fused into final layer; pooling via LDS histogram.

#define HD 128
#define SCHUNK 2048    // scan elements per block (256 thr * 8)

typedef __attribute__((ext_vector_type(4))) float f32x4;
typedef __attribute__((ext_vector_type(8))) float f32x8;
typedef __attribute__((ext_vector_type(8))) _Float16 f16x8;

// ---- CSR build ------------------------------------------------------------
__global__ __launch_bounds__(256) void k_deg(const int* __restrict__ dst, int E,
                                             int* __restrict__ cnt){
  int e = blockIdx.x * 256 + threadIdx.x;
  if (e < E) atomicAdd(&cnt[dst[e]], 1);
}

__global__ __launch_bounds__(256) void k_scan_part(const int* __restrict__ cnt,
                                                   int* __restrict__ bsum, int N){
  __shared__ int red[256];
  int t = threadIdx.x;
  int lo = blockIdx.x * SCHUNK + t * 8;
  int s = 0;
#pragma unroll
  for (int k = 0; k < 8; ++k){
    int i = lo + k;
    s += (i < N) ? cnt[i] : 0;
  }
  red[t] = s;
  __syncthreads();
  for (int off = 128; off > 0; off >>= 1){
    if (t < off) red[t] += red[t + off];
    __syncthreads();
  }
  if (t == 0) bsum[blockIdx.x] = red[0];
}

__global__ __launch_bounds__(1024) void k_scan_mid(const int* __restrict__ bsum,
                                                   int* __restrict__ boff, int nb,
                                                   int* __restrict__ rp, int N, int E){
  __shared__ int part[1024];
  int t = threadIdx.x;
  part[t] = (t < nb) ? bsum[t] : 0;
  __syncthreads();
  for (int off = 1; off < 1024; off <<= 1){
    int v = (t >= off) ? part[t - off] : 0;
    __syncthreads();
    part[t] += v;
    __syncthreads();
  }
  if (t < nb) boff[t] = (t == 0) ? 0 : part[t - 1];
  if (t == 0) rp[N] = E;
}

__global__ __launch_bounds__(256) void k_scan_apply(const int* __restrict__ cnt,
                                                    const int* __restrict__ boff,
                                                    int* __restrict__ rp,
                                                    float* __restrict__ dinv, int N){
  __shared__ int tsum[256];
  int t = threadIdx.x;
  int lo = blockIdx.x * SCHUNK + t * 8;
  int v[8];
  int s = 0;
#pragma unroll
  for (int k = 0; k < 8; ++k){
    int i = lo + k;
    v[k] = (i < N) ? cnt[i] : 0;
    s += v[k];
  }
  tsum[t] = s;
  __syncthreads();
  for (int off = 1; off < 256; off <<= 1){
    int u = (t >= off) ? tsum[t - off] : 0;
    __syncthreads();
    tsum[t] += u;
    __syncthreads();
  }
  int base = boff[blockIdx.x] + ((t == 0) ? 0 : tsum[t - 1]);
#pragma unroll
  for (int k = 0; k < 8; ++k){
    int i = lo + k;
    if (i < N){
      rp[i] = base;
      dinv[i] = rsqrtf((float)v[k] + 1.0f);
      base += v[k];
    }
  }
}

// fill: consumes cnt as cursor (atomicSub). 4B record: (deg1<<18) | src.
__global__ __launch_bounds__(256) void k_fill(const int* __restrict__ src,
                                              const int* __restrict__ dst, int E,
                                              const int* __restrict__ rp,
                                              int* cnt,
                                              const float* __restrict__ dinv,
                                              unsigned* __restrict__ col){
  int e = blockIdx.x * 256 + threadIdx.x;
  if (e >= E) return;
  int s = src[e], d = dst[e];
  int pos = rp[d] + atomicSub(&cnt[d], 1) - 1;
  float di = dinv[s];                       // = rsqrt(deg1), deg1 = deg+1
  int deg1 = (int)(1.0f / (di * di) + 0.5f);
  col[pos] = ((unsigned)deg1 << 18) | (unsigned)s;
}

// ---- weight prep: fp32 -> fp16 (RTN), bias sum -----------------------------
__global__ __launch_bounds__(256) void k_prep_w(const float* __restrict__ Wc,
                                                const float* __restrict__ Wr,
                                                const float* __restrict__ We,
                                                const float* __restrict__ bc,
                                                const float* __restrict__ br,
                                                _Float16* __restrict__ WcF,
                                                _Float16* __restrict__ WrF,
                                                _Float16* __restrict__ WeF,
                                                float* __restrict__ bias_sum){
  int i = blockIdx.x * 256 + threadIdx.x;
  if (i < HD * HD){
    WcF[i] = (_Float16)Wc[i];
    WrF[i] = (_Float16)Wr[i];
    WeF[i] = (_Float16)We[i];
  }
  if (i < HD) bias_sum[i] = bc[i] + br[i];
}

// ---- encoder GEMM: XsH = fp16(x @ We^T + b_enc), We LDS-staged -------------
__global__ __launch_bounds__(256) void k_enc(
    const float* __restrict__ A1f,
    const _Float16* __restrict__ W1,
    const float* __restrict__ bias,
    _Float16* __restrict__ outXsH,
    int N){
  __shared__ _Float16 wsm[HD * HD];
  f16x8* smv = (f16x8*)wsm;
  int t = threadIdx.x;
  {
    const f16x8* g1 = (const f16x8*)W1;
    for (int i = t; i < HD * HD / 8; i += 256){
      int row = i >> 4, slot = i & 15;
      smv[(row << 4) | (slot ^ (row & 7))] = g1[i];
    }
  }
  __syncthreads();

  int wid = blockIdx.x * 4 + (t >> 6);
  int row0 = wid * 32;
  bool act = (row0 < N);
  int rowb = act ? row0 : 0;
  int lane = t & 63;
  int r = lane & 15;
  int kg = lane >> 4;

  f32x4 acc[2][8];
#pragma unroll
  for (int s = 0; s < 2; ++s)
#pragma unroll
    for (int c = 0; c < 8; ++c) acc[s][c] = (f32x4)0.0f;

#pragma unroll
  for (int kst = 0; kst < 4; ++kst){
    int k0 = kst * 32 + kg * 8;
    f16x8 a1[2];
#pragma unroll
    for (int s = 0; s < 2; ++s){
      f32x8 u = *(const f32x8*)(A1f + (size_t)(rowb + s * 16 + r) * HD + k0);
#pragma unroll
      for (int i = 0; i < 8; ++i) a1[s][i] = (_Float16)u[i];
    }
    int swz = (kst * 4 + kg) ^ (r & 7);
#pragma unroll
    for (int ct = 0; ct < 8; ++ct){
      f16x8 b1 = smv[((ct * 16 + r) << 4) | swz];
#pragma unroll
      for (int s = 0; s < 2; ++s)
        acc[s][ct] = __builtin_amdgcn_mfma_f32_16x16x32_f16(a1[s], b1, acc[s][ct], 0, 0, 0);
    }
  }
  if (act){
#pragma unroll
    for (int s = 0; s < 2; ++s)
#pragma unroll
      for (int ct = 0; ct < 8; ++ct){
        int cc = ct * 16 + r;
        float bv = bias[cc];
#pragma unroll
        for (int j = 0; j < 4; ++j){
          int rr = row0 + s * 16 + kg * 4 + j;
          outXsH[(size_t)rr * HD + cc] = (_Float16)(acc[s][ct][j] + bv);
        }
      }
  }
}

// ---- fused layer: gather U into LDS, then two-pass fp16 MFMA ---------------
// Block owns 128 node-rows. Phase 1: wave wv gathers U for its 32 nodes
// (quarter-wave per edge, 16B f16x8 gathers) into swizzled LDS tile.
// Phase 2: pass A acc += (U + (dinv^2-1)Xp) Wc^T (U from LDS); restage;
// pass B acc += Xp Wr^T; out = relu(acc+bias) -> Xn (or decode -> val).
__global__ __launch_bounds__(256) void k_layer(
    const _Float16* __restrict__ Xp,
    const float* __restrict__ dinv,
    const int* __restrict__ rp,
    const unsigned* __restrict__ col,
    const _Float16* __restrict__ W1,          // WcF
    const _Float16* __restrict__ W2,          // WrF
    const float* __restrict__ bias,
    _Float16* __restrict__ Xn,
    const float* __restrict__ Wd, const float* __restrict__ bd,
    float* __restrict__ val,
    int N, int decode){
  __shared__ _Float16 usm[HD * HD];           // U tile, swizzled, 32KB
  __shared__ _Float16 wsm[HD * HD];           // weight stage, swizzled, 32KB
  f16x8* uv  = (f16x8*)usm;
  f16x8* smv = (f16x8*)wsm;
  int t = threadIdx.x;

  // stage W1 (completes under the post-gather barrier)
  {
    const f16x8* g1 = (const f16x8*)W1;
    for (int i = t; i < HD * HD / 8; i += 256){
      int row = i >> 4, slot = i & 15;
      smv[(row << 4) | (slot ^ (row & 7))] = g1[i];
    }
  }

  int wv = t >> 6;
  int lane = t & 63;
  int q = lane >> 4;       // edge slot 0..3
  int ql = lane & 15;      // channel group
  int blk0 = (int)blockIdx.x * 128;

  // ---- phase 1: gather 32 nodes per wave ----
  for (int k = 0; k < 32; ++k){
    int ln = wv * 32 + k;
    int node = blk0 + ln;
    float acc[8];
#pragma unroll
    for (int i = 0; i < 8; ++i) acc[i] = 0.f;
    if (node < N){
      int b = rp[node], e = rp[node + 1];
      int j = b + q;
      for (; j + 12 < e; j += 16){
        unsigned r0 = col[j];
        unsigned r1 = col[j + 4];
        unsigned r2 = col[j + 8];
        unsigned r3 = col[j + 12];
        float w0 = rsqrtf((float)(r0 >> 18));
        float w1 = rsqrtf((float)(r1 >> 18));
        float w2 = rsqrtf((float)(r2 >> 18));
        float w3 = rsqrtf((float)(r3 >> 18));
        f16x8 v0 = ((const f16x8*)(Xp + (size_t)(r0 & 0x3FFFFu) * HD))[ql];
        f16x8 v1 = ((const f16x8*)(Xp + (size_t)(r1 & 0x3FFFFu) * HD))[ql];
        f16x8 v2 = ((const f16x8*)(Xp + (size_t)(r2 & 0x3FFFFu) * HD))[ql];
        f16x8 v3 = ((const f16x8*)(Xp + (size_t)(r3 & 0x3FFFFu) * HD))[ql];
#pragma unroll
        for (int i = 0; i < 8; ++i) acc[i] = fmaf(w0, (float)v0[i], acc[i]);
#pragma unroll
        for (int i = 0; i < 8; ++i) acc[i] = fmaf(w1, (float)v1[i], acc[i]);
#pragma unroll
        for (int i = 0; i < 8; ++i) acc[i] = fmaf(w2, (float)v2[i], acc[i]);
#pragma unroll
        for (int i = 0; i < 8; ++i) acc[i] = fmaf(w3, (float)v3[i], acc[i]);
      }
      for (; j < e; j += 4){
        unsigned r0 = col[j];
        float w0 = rsqrtf((float)(r0 >> 18));
        f16x8 v0 = ((const f16x8*)(Xp + (size_t)(r0 & 0x3FFFFu) * HD))[ql];
#pragma unroll
        for (int i = 0; i < 8; ++i) acc[i] = fmaf(w0, (float)v0[i], acc[i]);
      }
      float dn = dinv[node];
#pragma unroll
      for (int i = 0; i < 8; ++i){
        acc[i] += __shfl_xor(acc[i], 16, 64);
        acc[i] += __shfl_xor(acc[i], 32, 64);
        acc[i] *= dn;
      }
    }
    if (q == 0){
      f16x8 o;
#pragma unroll
      for (int i = 0; i < 8; ++i) o[i] = (_Float16)acc[i];
      uv[(ln << 4) | (ql ^ (ln & 7))] = o;    // swizzled store
    }
  }
  __syncthreads();

  // ---- phase 2: MFMA ----
  int row0 = blk0 + wv * 32;
  bool act = (row0 < N);
  int rowb = act ? row0 : 0;
  int r = lane & 15;
  int kg = lane >> 4;

  f32x4 acc2[2][8];
#pragma unroll
  for (int s = 0; s < 2; ++s)
#pragma unroll
    for (int c = 0; c < 8; ++c) acc2[s][c] = (f32x4)0.0f;

  float sr[2];
#pragma unroll
  for (int s = 0; s < 2; ++s){
    float d = dinv[rowb + s * 16 + r];
    sr[s] = d * d - 1.0f;
  }

  // pass A: (U + sr*Xp) x Wc
#pragma unroll
  for (int kst = 0; kst < 4; ++kst){
    int k0 = kst * 32 + kg * 8;
    int swz = (kst * 4 + kg) ^ (r & 7);
    f16x8 a1[2];
#pragma unroll
    for (int s = 0; s < 2; ++s){
      int lrow = wv * 32 + s * 16 + r;
      f16x8 uh = uv[(lrow << 4) | swz];       // lrow&7 == r&7
      f16x8 xv = *(const f16x8*)(Xp + (size_t)(rowb + s * 16 + r) * HD + k0);
#pragma unroll
      for (int i = 0; i < 8; ++i)
        a1[s][i] = (_Float16)fmaf(sr[s], (float)xv[i], (float)uh[i]);
    }
#pragma unroll
    for (int ct = 0; ct < 8; ++ct){
      f16x8 b1 = smv[((ct * 16 + r) << 4) | swz];
#pragma unroll
      for (int s = 0; s < 2; ++s)
        acc2[s][ct] = __builtin_amdgcn_mfma_f32_16x16x32_f16(a1[s], b1, acc2[s][ct], 0, 0, 0);
    }
  }

  // restage W2
  __syncthreads();
  {
    const f16x8* g2 = (const f16x8*)W2;
    for (int i = t; i < HD * HD / 8; i += 256){
      int row = i >> 4, slot = i & 15;
      smv[(row << 4) | (slot ^ (row & 7))] = g2[i];
    }
  }
  __syncthreads();

  // pass B: Xp x Wr
#pragma unroll
  for (int kst = 0; kst < 4; ++kst){
    int k0 = kst * 32 + kg * 8;
    int swz = (kst * 4 + kg) ^ (r & 7);
    f16x8 a2[2];
#pragma unroll
    for (int s = 0; s < 2; ++s)
      a2[s] = *(const f16x8*)(Xp + (size_t)(rowb + s * 16 + r) * HD + k0);
#pragma unroll
    for (int ct = 0; ct < 8; ++ct){
      f16x8 b2 = smv[((ct * 16 + r) << 4) | swz];
#pragma unroll
      for (int s = 0; s < 2; ++s)
        acc2[s][ct] = __builtin_amdgcn_mfma_f32_16x16x32_f16(a2[s], b2, acc2[s][ct], 0, 0, 0);
    }
  }

  // epilogue: C/D layout col = lane&15, row = kg*4 + reg
  float rowp[2][4] = {{0.f,0.f,0.f,0.f},{0.f,0.f,0.f,0.f}};
#pragma unroll
  for (int s = 0; s < 2; ++s){
#pragma unroll
    for (int ct = 0; ct < 8; ++ct){
      int cc = ct * 16 + r;
      float bv = bias[cc];
      float wdv = decode ? Wd[cc] : 0.f;
#pragma unroll
      for (int j = 0; j < 4; ++j){
        float v = fmaxf(acc2[s][ct][j] + bv, 0.0f);
        if (decode){
          rowp[s][j] += v * wdv;
        } else if (act){
          int rr = row0 + s * 16 + kg * 4 + j;
          Xn[(size_t)rr * HD + cc] = (_Float16)v;
        }
      }
    }
  }
  if (decode && act){
    float bd0 = bd[0];
#pragma unroll
    for (int s = 0; s < 2; ++s)
#pragma unroll
      for (int j = 0; j < 4; ++j){
        float tt = rowp[s][j];
        tt += __shfl_xor(tt, 1, 64);
        tt += __shfl_xor(tt, 2, 64);
        tt += __shfl_xor(tt, 4, 64);
        tt += __shfl_xor(tt, 8, 64);
        if (r == 0) val[row0 + s * 16 + kg * 4 + j] = tt + bd0;
      }
  }
}

// ---- pooling: LDS histogram per block, few global atomics ------------------
#define POOL_CHUNK 1024
__global__ __launch_bounds__(256) void k_pool(const float* __restrict__ val,
                                              const int* __restrict__ batch,
                                              float* __restrict__ out, int N, int G){
  __shared__ float acc[4096];
  int t = threadIdx.x;
  int lo = blockIdx.x * POOL_CHUNK;
  int hi = min(lo + POOL_CHUNK, N);
  if (G <= 4096){
    for (int i = t; i < G; i += 256) acc[i] = 0.f;
    __syncthreads();
    for (int i = lo + t; i < hi; i += 256) atomicAdd(&acc[batch[i]], val[i]);
    __syncthreads();
    for (int i = t; i < G; i += 256){
      float v = acc[i];
      if (v != 0.f) atomicAdd(&out[i], v);
    }
  } else {
    for (int i = lo + t; i < hi; i += 256) atomicAdd(&out[batch[i]], val[i]);
  }
}

// ---- launcher ---------------------------------------------------------------
extern "C" void kernel_launch(void* const* d_in, const int* in_sizes, int n_in,
                              void* d_out, int out_size, void* d_ws, size_t ws_size,
                              hipStream_t stream){
  const float* x      = (const float*)d_in[0];
  const int*   ei     = (const int*)d_in[1];
  const int*   batch  = (const int*)d_in[2];
  const float* W_enc  = (const float*)d_in[3];
  const float* b_enc  = (const float*)d_in[4];
  const float* W_conv = (const float*)d_in[5];
  const float* b_conv = (const float*)d_in[6];
  const float* W_res  = (const float*)d_in[7];
  const float* b_res  = (const float*)d_in[8];
  const float* W_dec  = (const float*)d_in[9];
  const float* b_dec  = (const float*)d_in[10];

  const int N = in_sizes[0] / HD;
  const int E = in_sizes[1] / 2;
  float* out = (float*)d_out;

  char* ws = (char*)d_ws;
  size_t off = 0;
  auto alloc = [&](size_t bytes) -> char* {
    char* p = ws + off;
    off += (bytes + 255) & ~(size_t)255;
    return p;
  };
  int*   cnt   = (int*)  alloc((size_t)N * 4);
  int*   rp    = (int*)  alloc(((size_t)N + 1) * 4);
  float* dinv  = (float*)alloc((size_t)N * 4);
  int*   bsum  = (int*)  alloc(1024 * 4);
  int*   boff  = (int*)  alloc(1024 * 4);
  unsigned* col= (unsigned*)alloc((size_t)E * 4);
  _Float16* XsA= (_Float16*)alloc((size_t)N * HD * 2);
  _Float16* XsB= (_Float16*)alloc((size_t)N * HD * 2);
  float* val   = (float*)alloc((size_t)N * 4);
  _Float16* WcF = (_Float16*)alloc((size_t)HD * HD * 2);
  _Float16* WrF = (_Float16*)alloc((size_t)HD * HD * 2);
  _Float16* WeF = (_Float16*)alloc((size_t)HD * HD * 2);
  float* bias_sum = (float*)alloc((size_t)HD * 4);

  hipMemsetAsync(cnt, 0, (size_t)N * 4, stream);
  hipMemsetAsync(out, 0, (size_t)out_size * 4, stream);

  const int* src = ei;
  const int* dst = ei + E;

  int nb = (N + SCHUNK - 1) / SCHUNK;

  k_deg       <<<(E + 255) / 256, 256, 0, stream>>>(dst, E, cnt);
  k_scan_part <<<nb, 256, 0, stream>>>(cnt, bsum, N);
  k_scan_mid  <<<1, 1024, 0, stream>>>(bsum, boff, nb, rp, N, E);
  k_scan_apply<<<nb, 256, 0, stream>>>(cnt, boff, rp, dinv, N);
  k_fill      <<<(E + 255) / 256, 256, 0, stream>>>(src, dst, E, rp, cnt, dinv, col);
  k_prep_w    <<<(HD * HD + 255) / 256, 256, 0, stream>>>(W_conv, W_res, W_enc, b_conv, b_res,
                                                          WcF, WrF, WeF, bias_sum);

  int enc_blocks = ((N + 31) / 32 + 3) / 4;
  int layer_blocks = (N + 127) / 128;

  // encoder: XsA = fp16(x @ W_enc^T + b_enc)
  k_enc<<<enc_blocks, 256, 0, stream>>>(x, WeF, b_enc, XsA, N);

  const _Float16* cur = XsA;
  _Float16* nxt = XsB;
  for (int l = 0; l < 5; ++l){
    int last = (l == 4);
    k_layer<<<layer_blocks, 256, 0, stream>>>(cur, dinv, rp, col, WcF, WrF,
                                              bias_sum, nxt,
                                              W_dec, b_dec, val, N, last);
    const _Float16* tmp = nxt;
    nxt = (_Float16*)cur;
    cur = tmp;
  }

  k_pool<<<(N + POOL_CHUNK - 1) / POOL_CHUNK, 256, 0, stream>>>(val, batch, out, N, out_size);
}

// Round 12
// 552.774 us; speedup vs baseline: 2.0115x; 2.0115x over previous
//
#include <hip/hip_runtime.h>
#include <hip/hip_bf16.h>
#include <stdint.h>

// GraphCON-GCN on MI355X.
// Algebra: with DT=ALPHA=GAMMA=1, Xs_{l+1} = relu(gcn+res); Y drops out.
// z = (A.Xs) Wc^T + (dinv^2-1) Xs Wc^T + Xs Wr^T + (b_c+b_r)  [self-term folded
// in-register in the GEMM]. State fp16 (XsH); agg gathers fp16, U fp16.
// r12 CSR build = tile multisplit (replaces deg+3scans+fill ~155us whose cost
// was line-granular scatter amplification, WRITE ~64B/edge):
//   k_count:  per-4096-edge-tile bucket(dst>>9) histograms -> bcnt (coalesced)
//   k_btot:   per-bucket column exclusive-prefix over tiles -> bpreT, totals
//   k_gscan:  scan bucket totals -> gstart (bucket base in col); rp[N]=E
//   k_scatter:re-read tile, LDS-stage records in bucket-grouped order with
//             COMPUTED positions, dump as coalesced bursts -> tmp
//   k_build:  per bucket: deg histogram + local scan -> rp/dinv (coalesced),
//             LDS scatter to exact CSR order, coalesced dump -> col
// col record = src only (17b); agg loads dinv[src] (L2-resident).
// Differs from r9's failed k_bin: no per-bucket micro-staging, no serial
// per-wave flush with dependent global-atomic RTTs, no hot-loop global
// atomics; all global writes coalesced/bursty. k_build has an overflow
// fallback so correctness never depends on load balance.
// k_agg/k_gemm = r10 (fusion r11 failed: 64KB LDS -> 8 waves/CU kills
// gather MLP; gather needs ~25 waves/CU).

#define HD 128
#define BSH 9                 // bucket = 512 nodes
#define TILE 4096             // edges per multisplit tile
#define NBPAD 1024            // max tiles (E <= 4M)
#define BCAP 10240            // k_build LDS col capacity (40KB)

typedef __attribute__((ext_vector_type(4))) float f32x4;
typedef __attribute__((ext_vector_type(8))) float f32x8;
typedef __attribute__((ext_vector_type(8))) _Float16 f16x8;

// ---- CSR build: tile multisplit -------------------------------------------
__global__ __launch_bounds__(256) void k_count(const int* __restrict__ dst, int E,
                                               int* __restrict__ bcnt){
  __shared__ int hist[256];
  int t = threadIdx.x;
  hist[t] = 0;
  __syncthreads();
  int base = blockIdx.x * TILE;
#pragma unroll
  for (int k = 0; k < TILE / 256; ++k){
    int e = base + k * 256 + t;
    if (e < E) atomicAdd(&hist[dst[e] >> BSH], 1);
  }
  __syncthreads();
  bcnt[blockIdx.x * 256 + t] = hist[t];
}

// one block per bucket: exclusive prefix of its column over tiles
__global__ __launch_bounds__(256) void k_btot(const int* __restrict__ bcnt,
                                              int* __restrict__ bpreT,
                                              int* __restrict__ btot, int NB){
  __shared__ int arr[NBPAD];
  __shared__ int ps[256];
  int b = blockIdx.x, t = threadIdx.x;
  for (int i = t; i < NBPAD; i += 256) arr[i] = (i < NB) ? bcnt[i * 256 + b] : 0;
  __syncthreads();
  int v0 = arr[4 * t], v1 = arr[4 * t + 1], v2 = arr[4 * t + 2], v3 = arr[4 * t + 3];
  ps[t] = v0 + v1 + v2 + v3;
  __syncthreads();
  for (int off = 1; off < 256; off <<= 1){
    int v = (t >= off) ? ps[t - off] : 0;
    __syncthreads();
    ps[t] += v;
    __syncthreads();
  }
  int base0 = (t == 0) ? 0 : ps[t - 1];
  arr[4 * t] = base0;
  arr[4 * t + 1] = base0 + v0;
  arr[4 * t + 2] = base0 + v0 + v1;
  arr[4 * t + 3] = base0 + v0 + v1 + v2;
  __syncthreads();
  for (int i = t; i < NB; i += 256) bpreT[b * NBPAD + i] = arr[i];
  if (t == 255) btot[b] = ps[255];
}

__global__ __launch_bounds__(256) void k_gscan(const int* __restrict__ btot,
                                               int* __restrict__ gstart, int nbuck,
                                               int* __restrict__ rp, int N, int E){
  __shared__ int sm[256];
  int t = threadIdx.x;
  sm[t] = (t < nbuck) ? btot[t] : 0;
  __syncthreads();
  for (int off = 1; off < 256; off <<= 1){
    int v = (t >= off) ? sm[t - off] : 0;
    __syncthreads();
    sm[t] += v;
    __syncthreads();
  }
  if (t < nbuck) gstart[t] = (t == 0) ? 0 : sm[t - 1];
  if (t == 0) rp[N] = E;
}

// stage tile's records bucket-grouped in LDS (computed positions), dump
// as coalesced bursts to bucket-contiguous tmp.
__global__ __launch_bounds__(256) void k_scatter(const int* __restrict__ src,
                                                 const int* __restrict__ dst, int E,
                                                 const int* __restrict__ bpreT,
                                                 const int* __restrict__ gstart,
                                                 unsigned* __restrict__ tmp){
  __shared__ unsigned srec[TILE];
  __shared__ unsigned char sbin[TILE];
  __shared__ int hist[256], scn[256], cur[256], lstart[256];
  int t = threadIdx.x, blk = blockIdx.x;
  hist[t] = 0; cur[t] = 0;
  __syncthreads();
  int base = blk * TILE;
#pragma unroll
  for (int k = 0; k < TILE / 256; ++k){
    int e = base + k * 256 + t;
    if (e < E) atomicAdd(&hist[dst[e] >> BSH], 1);
  }
  __syncthreads();
  scn[t] = hist[t];
  __syncthreads();
  for (int off = 1; off < 256; off <<= 1){
    int v = (t >= off) ? scn[t - off] : 0;
    __syncthreads();
    scn[t] += v;
    __syncthreads();
  }
  lstart[t] = (t == 0) ? 0 : scn[t - 1];
  __syncthreads();
#pragma unroll
  for (int k = 0; k < TILE / 256; ++k){
    int e = base + k * 256 + t;
    if (e < E){
      int d = dst[e], s = src[e], b = d >> BSH;
      int slot = atomicAdd(&cur[b], 1);
      int idx = lstart[b] + slot;
      srec[idx] = ((unsigned)(d & ((1 << BSH) - 1)) << 17) | (unsigned)s;
      sbin[idx] = (unsigned char)b;
    }
  }
  __syncthreads();
  int cntT = min(TILE, E - base);
#pragma unroll
  for (int k = 0; k < TILE / 256; ++k){
    int i = k * 256 + t;
    if (i < cntT){
      int b = sbin[i];
      int pos = gstart[b] + bpreT[b * NBPAD + blk] + (i - lstart[b]);
      tmp[pos] = srec[i];
    }
  }
}

// per bucket: deg hist + local scan -> rp/dinv; LDS scatter -> exact CSR; dump.
__global__ __launch_bounds__(256) void k_build(const unsigned* __restrict__ tmp,
                                               const int* __restrict__ gstart, int nbuck,
                                               int* __restrict__ rp,
                                               float* __restrict__ dinv,
                                               unsigned* __restrict__ col, int N, int E){
  __shared__ unsigned lcol[BCAP];
  __shared__ int deg[512], rpl[512], cur[512];
  __shared__ int ps[256];
  int b = blockIdx.x, t = threadIdx.x;
  int lo = b << BSH;
  int nn = min(512, N - lo);
  int gbase = gstart[b];
  int gend = (b + 1 < nbuck) ? gstart[b + 1] : E;
  int count = gend - gbase;
  for (int i = t; i < 512; i += 256){ deg[i] = 0; cur[i] = 0; }
  __syncthreads();
  const unsigned* trec = tmp + gbase;
  for (int i = t; i < count; i += 256) atomicAdd(&deg[trec[i] >> 17], 1);
  __syncthreads();
  int a0 = deg[2 * t], a1 = deg[2 * t + 1];
  ps[t] = a0 + a1;
  __syncthreads();
  for (int off = 1; off < 256; off <<= 1){
    int v = (t >= off) ? ps[t - off] : 0;
    __syncthreads();
    ps[t] += v;
    __syncthreads();
  }
  int excl = (t == 0) ? 0 : ps[t - 1];
  rpl[2 * t] = excl;
  rpl[2 * t + 1] = excl + a0;
  __syncthreads();
  for (int i = t; i < nn; i += 256){
    rp[lo + i] = gbase + rpl[i];
    dinv[lo + i] = rsqrtf((float)deg[i] + 1.0f);
  }
  if (count <= BCAP){
    for (int i = t; i < count; i += 256){
      unsigned r = trec[i];
      int d = r >> 17;
      int pos = rpl[d] + atomicAdd(&cur[d], 1);
      lcol[pos] = r & 0x1FFFFu;
    }
    __syncthreads();
    for (int i = t; i < count; i += 256) col[gbase + i] = lcol[i];
  } else {                                    // overflow fallback (never expected)
    for (int i = t; i < count; i += 256){
      unsigned r = trec[i];
      int d = r >> 17;
      int pos = rpl[d] + atomicAdd(&cur[d], 1);
      col[gbase + pos] = r & 0x1FFFFu;
    }
  }
}

// ---- weight prep: fp32 -> fp16 (RTN), bias sum -----------------------------
__global__ __launch_bounds__(256) void k_prep_w(const float* __restrict__ Wc,
                                                const float* __restrict__ Wr,
                                                const float* __restrict__ We,
                                                const float* __restrict__ bc,
                                                const float* __restrict__ br,
                                                _Float16* __restrict__ WcF,
                                                _Float16* __restrict__ WrF,
                                                _Float16* __restrict__ WeF,
                                                float* __restrict__ bias_sum){
  int i = blockIdx.x * 256 + threadIdx.x;
  if (i < HD * HD){
    WcF[i] = (_Float16)Wc[i];
    WrF[i] = (_Float16)Wr[i];
    WeF[i] = (_Float16)We[i];
  }
  if (i < HD) bias_sum[i] = bc[i] + br[i];
}

// ---- per-layer aggregation: U = dinv[dst] * sum_e dinv[src]*XsH[src] -------
// One wave per node. Quarter-wave per edge; lane gathers f16x8 (16B);
// 16 lanes * 16B = 256B row. 4x unroll => 16 gathers in flight per wave.
__global__ __launch_bounds__(256) void k_agg(const _Float16* __restrict__ XsH,
                                             const float* __restrict__ dinv,
                                             const int* __restrict__ rp,
                                             const unsigned* __restrict__ col,
                                             _Float16* __restrict__ U,
                                             int N){
  int w = threadIdx.x >> 6;
  int lane = threadIdx.x & 63;
  int q = lane >> 4;       // edge slot 0..3
  int ql = lane & 15;      // channel group: cols ql*8 .. ql*8+7
  int node = blockIdx.x * 4 + w;
  if (node >= N) return;

  float acc[8];
#pragma unroll
  for (int i = 0; i < 8; ++i) acc[i] = 0.f;

  int b = rp[node], e = rp[node + 1];
  int j = b + q;
  for (; j + 12 < e; j += 16){
    unsigned c0 = col[j];
    unsigned c1 = col[j + 4];
    unsigned c2 = col[j + 8];
    unsigned c3 = col[j + 12];
    float w0 = dinv[c0];
    float w1 = dinv[c1];
    float w2 = dinv[c2];
    float w3 = dinv[c3];
    f16x8 v0 = ((const f16x8*)(XsH + (size_t)c0 * HD))[ql];
    f16x8 v1 = ((const f16x8*)(XsH + (size_t)c1 * HD))[ql];
    f16x8 v2 = ((const f16x8*)(XsH + (size_t)c2 * HD))[ql];
    f16x8 v3 = ((const f16x8*)(XsH + (size_t)c3 * HD))[ql];
#pragma unroll
    for (int i = 0; i < 8; ++i) acc[i] = fmaf(w0, (float)v0[i], acc[i]);
#pragma unroll
    for (int i = 0; i < 8; ++i) acc[i] = fmaf(w1, (float)v1[i], acc[i]);
#pragma unroll
    for (int i = 0; i < 8; ++i) acc[i] = fmaf(w2, (float)v2[i], acc[i]);
#pragma unroll
    for (int i = 0; i < 8; ++i) acc[i] = fmaf(w3, (float)v3[i], acc[i]);
  }
  for (; j < e; j += 4){
    unsigned c0 = col[j];
    float w0 = dinv[c0];
    f16x8 v0 = ((const f16x8*)(XsH + (size_t)c0 * HD))[ql];
#pragma unroll
    for (int i = 0; i < 8; ++i) acc[i] = fmaf(w0, (float)v0[i], acc[i]);
  }

  float dn = dinv[node];
#pragma unroll
  for (int i = 0; i < 8; ++i){
    acc[i] += __shfl_xor(acc[i], 16, 64);
    acc[i] += __shfl_xor(acc[i], 32, 64);
    acc[i] *= dn;
  }
  if (q == 0){
    f16x8 o;
#pragma unroll
    for (int i = 0; i < 8; ++i) o[i] = (_Float16)acc[i];
    ((f16x8*)(U + (size_t)node * HD))[ql] = o;
  }
}

// ---- fused fp16 GEMM, ONE weight matrix staged at a time (32KB LDS) --------
// two=false: out = cvt16(A1f) We^T + bias (encoder; A1f fp32).
// two=true:  pass A: acc += (U + (dinv^2-1)XsH) Wc^T; restage; pass B:
//            acc += XsH Wr^T; out = relu(acc + bias). Writes XsH fp16.
// decode: skip stores, val[row] = dot(out_row, Wd) + bd[0].
__global__ __launch_bounds__(256) void k_gemm(
    const float* __restrict__ A1f,            // encoder input x (fp32) or null
    const _Float16* __restrict__ A1h,         // U (fp16) or null
    const _Float16* A2h,                      // XsH (aliases outXsH) or null
    const _Float16* __restrict__ W1,          // WcF or WeF
    const _Float16* __restrict__ W2,          // WrF or null
    const float* __restrict__ dinvp,
    const float* __restrict__ bias,
    _Float16* outXsH,
    const float* __restrict__ Wd, const float* __restrict__ bd,
    float* __restrict__ val,
    int N, int relu, int decode){
  __shared__ _Float16 wsm[HD * HD];           // 32KB: [row][slot^]
  f16x8* smv = (f16x8*)wsm;
  int t = threadIdx.x;

  {
    const f16x8* g1 = (const f16x8*)W1;
    for (int i = t; i < HD * HD / 8; i += 256){
      int row = i >> 4, slot = i & 15;
      smv[(row << 4) | (slot ^ (row & 7))] = g1[i];
    }
  }
  __syncthreads();

  int wid = blockIdx.x * 4 + (t >> 6);
  int row0 = wid * 32;
  bool act = (row0 < N);
  int rowb = act ? row0 : 0;
  int lane = t & 63;
  int r = lane & 15;
  int kg = lane >> 4;

  f32x4 acc[2][8];
#pragma unroll
  for (int s = 0; s < 2; ++s)
#pragma unroll
    for (int c = 0; c < 8; ++c) acc[s][c] = (f32x4)0.0f;

  const bool two = (A2h != nullptr);
  float sr[2] = {0.f, 0.f};
  if (two){
#pragma unroll
    for (int s = 0; s < 2; ++s){
      float d = dinvp[rowb + s * 16 + r];
      sr[s] = d * d - 1.0f;
    }
  }

  // ---- pass A ----
#pragma unroll
  for (int kst = 0; kst < 4; ++kst){
    int k0 = kst * 32 + kg * 8;
    f16x8 a1[2];
#pragma unroll
    for (int s = 0; s < 2; ++s){
      size_t ao = (size_t)(rowb + s * 16 + r) * HD + k0;
      if (two){
        f16x8 uh = *(const f16x8*)(A1h + ao);
        f16x8 xv = *(const f16x8*)(A2h + ao);
#pragma unroll
        for (int i = 0; i < 8; ++i)
          a1[s][i] = (_Float16)fmaf(sr[s], (float)xv[i], (float)uh[i]);
      } else {
        f32x8 u = *(const f32x8*)(A1f + ao);
#pragma unroll
        for (int i = 0; i < 8; ++i) a1[s][i] = (_Float16)u[i];
      }
    }
    int swz = (kst * 4 + kg) ^ (r & 7);
#pragma unroll
    for (int ct = 0; ct < 8; ++ct){
      f16x8 b1 = smv[((ct * 16 + r) << 4) | swz];
#pragma unroll
      for (int s = 0; s < 2; ++s)
        acc[s][ct] = __builtin_amdgcn_mfma_f32_16x16x32_f16(a1[s], b1, acc[s][ct], 0, 0, 0);
    }
  }

  // ---- pass B ----
  if (two){
    __syncthreads();
    const f16x8* g2 = (const f16x8*)W2;
    for (int i = t; i < HD * HD / 8; i += 256){
      int row = i >> 4, slot = i & 15;
      smv[(row << 4) | (slot ^ (row & 7))] = g2[i];
    }
    __syncthreads();
#pragma unroll
    for (int kst = 0; kst < 4; ++kst){
      int k0 = kst * 32 + kg * 8;
      f16x8 a2[2];
#pragma unroll
      for (int s = 0; s < 2; ++s)
        a2[s] = *(const f16x8*)(A2h + (size_t)(rowb + s * 16 + r) * HD + k0);
      int swz = (kst * 4 + kg) ^ (r & 7);
#pragma unroll
      for (int ct = 0; ct < 8; ++ct){
        f16x8 b2 = smv[((ct * 16 + r) << 4) | swz];
#pragma unroll
        for (int s = 0; s < 2; ++s)
          acc[s][ct] = __builtin_amdgcn_mfma_f32_16x16x32_f16(a2[s], b2, acc[s][ct], 0, 0, 0);
      }
    }
  }

  // epilogue: C/D layout col = lane&15, row = kg*4 + reg
  float rowp[2][4] = {{0.f,0.f,0.f,0.f},{0.f,0.f,0.f,0.f}};
#pragma unroll
  for (int s = 0; s < 2; ++s){
#pragma unroll
    for (int ct = 0; ct < 8; ++ct){
      int cc = ct * 16 + r;
      float bv = bias[cc];
      float wdv = decode ? Wd[cc] : 0.f;
#pragma unroll
      for (int j = 0; j < 4; ++j){
        float v = acc[s][ct][j] + bv;
        if (relu) v = fmaxf(v, 0.0f);
        if (decode){
          rowp[s][j] += v * wdv;
        } else if (act){
          int rr = row0 + s * 16 + kg * 4 + j;
          outXsH[(size_t)rr * HD + cc] = (_Float16)v;
        }
      }
    }
  }
  if (decode && act){
    float bd0 = bd[0];
#pragma unroll
    for (int s = 0; s < 2; ++s)
#pragma unroll
      for (int j = 0; j < 4; ++j){
        float tt = rowp[s][j];
        tt += __shfl_xor(tt, 1, 64);
        tt += __shfl_xor(tt, 2, 64);
        tt += __shfl_xor(tt, 4, 64);
        tt += __shfl_xor(tt, 8, 64);
        if (r == 0) val[row0 + s * 16 + kg * 4 + j] = tt + bd0;
      }
  }
}

// ---- pooling: LDS histogram per block, few global atomics ------------------
#define POOL_CHUNK 1024
__global__ __launch_bounds__(256) void k_pool(const float* __restrict__ val,
                                              const int* __restrict__ batch,
                                              float* __restrict__ out, int N, int G){
  __shared__ float acc[4096];
  int t = threadIdx.x;
  int lo = blockIdx.x * POOL_CHUNK;
  int hi = min(lo + POOL_CHUNK, N);
  if (G <= 4096){
    for (int i = t; i < G; i += 256) acc[i] = 0.f;
    __syncthreads();
    for (int i = lo + t; i < hi; i += 256) atomicAdd(&acc[batch[i]], val[i]);
    __syncthreads();
    for (int i = t; i < G; i += 256){
      float v = acc[i];
      if (v != 0.f) atomicAdd(&out[i], v);
    }
  } else {
    for (int i = lo + t; i < hi; i += 256) atomicAdd(&out[batch[i]], val[i]);
  }
}

// ---- launcher ---------------------------------------------------------------
extern "C" void kernel_launch(void* const* d_in, const int* in_sizes, int n_in,
                              void* d_out, int out_size, void* d_ws, size_t ws_size,
                              hipStream_t stream){
  const float* x      = (const float*)d_in[0];
  const int*   ei     = (const int*)d_in[1];
  const int*   batch  = (const int*)d_in[2];
  const float* W_enc  = (const float*)d_in[3];
  const float* b_enc  = (const float*)d_in[4];
  const float* W_conv = (const float*)d_in[5];
  const float* b_conv = (const float*)d_in[6];
  const float* W_res  = (const float*)d_in[7];
  const float* b_res  = (const float*)d_in[8];
  const float* W_dec  = (const float*)d_in[9];
  const float* b_dec  = (const float*)d_in[10];

  const int N = in_sizes[0] / HD;
  const int E = in_sizes[1] / 2;
  const int NB = (E + TILE - 1) / TILE;            // <= NBPAD
  const int nbuck = (N + (1 << BSH) - 1) >> BSH;   // <= 256
  float* out = (float*)d_out;

  char* ws = (char*)d_ws;
  size_t off = 0;
  auto alloc = [&](size_t bytes) -> char* {
    char* p = ws + off;
    off += (bytes + 255) & ~(size_t)255;
    return p;
  };
  int*   rp    = (int*)  alloc(((size_t)N + 1) * 4);
  float* dinv  = (float*)alloc((size_t)N * 4);
  int*   bcnt  = (int*)  alloc((size_t)NBPAD * 256 * 4);
  int*   bpreT = (int*)  alloc((size_t)256 * NBPAD * 4);
  int*   btot  = (int*)  alloc(256 * 4);
  int*   gstart= (int*)  alloc(256 * 4);
  unsigned* tmp= (unsigned*)alloc((size_t)E * 4);
  unsigned* col= (unsigned*)alloc((size_t)E * 4);
  _Float16* XsH= (_Float16*)alloc((size_t)N * HD * 2);
  _Float16* U  = (_Float16*)alloc((size_t)N * HD * 2);
  float* val   = (float*)alloc((size_t)N * 4);
  _Float16* WcF = (_Float16*)alloc((size_t)HD * HD * 2);
  _Float16* WrF = (_Float16*)alloc((size_t)HD * HD * 2);
  _Float16* WeF = (_Float16*)alloc((size_t)HD * HD * 2);
  float* bias_sum = (float*)alloc((size_t)HD * 4);

  hipMemsetAsync(out, 0, (size_t)out_size * 4, stream);

  const int* src = ei;
  const int* dst = ei + E;

  k_count  <<<NB, 256, 0, stream>>>(dst, E, bcnt);
  k_btot   <<<nbuck, 256, 0, stream>>>(bcnt, bpreT, btot, NB);
  k_gscan  <<<1, 256, 0, stream>>>(btot, gstart, nbuck, rp, N, E);
  k_scatter<<<NB, 256, 0, stream>>>(src, dst, E, bpreT, gstart, tmp);
  k_build  <<<nbuck, 256, 0, stream>>>(tmp, gstart, nbuck, rp, dinv, col, N, E);
  k_prep_w <<<(HD * HD + 255) / 256, 256, 0, stream>>>(W_conv, W_res, W_enc, b_conv, b_res,
                                                       WcF, WrF, WeF, bias_sum);

  int gemm_blocks = ((N + 31) / 32 + 3) / 4;
  int node_blocks = (N + 3) / 4;

  // encoder: XsH = fp16(x @ W_enc^T + b_enc)
  k_gemm<<<gemm_blocks, 256, 0, stream>>>(x, nullptr, nullptr, WeF, nullptr,
                                          nullptr, b_enc, XsH,
                                          nullptr, nullptr, nullptr, N, 0, 0);

  for (int l = 0; l < 5; ++l){
    k_agg<<<node_blocks, 256, 0, stream>>>(XsH, dinv, rp, col, U, N);
    int last = (l == 4);
    k_gemm<<<gemm_blocks, 256, 0, stream>>>(nullptr, U, XsH, WcF, WrF,
                                            dinv, bias_sum, XsH,
                                            W_dec, b_dec, val, N, 1, last);
  }

  k_pool<<<(N + POOL_CHUNK - 1) / POOL_CHUNK, 256, 0, stream>>>(val, batch, out, N, out_size);
}

// Round 13
// 545.493 us; speedup vs baseline: 2.0383x; 1.0133x over previous
//
#include <hip/hip_runtime.h>
#include <hip/hip_bf16.h>
#include <stdint.h>

// GraphCON-GCN on MI355X.
// Algebra: with DT=ALPHA=GAMMA=1, Xs_{l+1} = relu(gcn+res); Y drops out.
// z = (A.Xs) Wc^T + (dinv^2-1) Xs Wc^T + Xs Wr^T + (b_c+b_r)  [self-term folded
// in-register in the GEMM]. State fp16 (XsH); agg gathers fp16, U fp16.
// CSR build = tile multisplit (r12, ~60us): count/btot/gscan/scatter/build,
// all global writes coalesced (kills the ~64B/edge scatter amplification).
// r13: k_agg inner loop in packed fp16 (v_pk_fma_f16): 4 pk_fma per edge vs
// 8 cvt + 8 fma — VALUBusy was 41% of the 63us dispatch.
// GEMM: fp16 MFMA, one 32KB weight matrix LDS-staged at a time.
// Decode fused into final GEMM; pooling via LDS histogram.

#define HD 128
#define BSH 9                 // bucket = 512 nodes
#define TILE 4096             // edges per multisplit tile
#define NBPAD 1024            // max tiles (E <= 4M)
#define BCAP 10240            // k_build LDS col capacity (40KB)

typedef __attribute__((ext_vector_type(4))) float f32x4;
typedef __attribute__((ext_vector_type(8))) float f32x8;
typedef __attribute__((ext_vector_type(8))) _Float16 f16x8;
typedef __attribute__((ext_vector_type(2))) _Float16 f16x2;

// ---- CSR build: tile multisplit -------------------------------------------
__global__ __launch_bounds__(256) void k_count(const int* __restrict__ dst, int E,
                                               int* __restrict__ bcnt){
  __shared__ int hist[256];
  int t = threadIdx.x;
  hist[t] = 0;
  __syncthreads();
  int base = blockIdx.x * TILE;
#pragma unroll
  for (int k = 0; k < TILE / 256; ++k){
    int e = base + k * 256 + t;
    if (e < E) atomicAdd(&hist[dst[e] >> BSH], 1);
  }
  __syncthreads();
  bcnt[blockIdx.x * 256 + t] = hist[t];
}

// one block per bucket: exclusive prefix of its column over tiles
__global__ __launch_bounds__(256) void k_btot(const int* __restrict__ bcnt,
                                              int* __restrict__ bpreT,
                                              int* __restrict__ btot, int NB){
  __shared__ int arr[NBPAD];
  __shared__ int ps[256];
  int b = blockIdx.x, t = threadIdx.x;
  for (int i = t; i < NBPAD; i += 256) arr[i] = (i < NB) ? bcnt[i * 256 + b] : 0;
  __syncthreads();
  int v0 = arr[4 * t], v1 = arr[4 * t + 1], v2 = arr[4 * t + 2], v3 = arr[4 * t + 3];
  ps[t] = v0 + v1 + v2 + v3;
  __syncthreads();
  for (int off = 1; off < 256; off <<= 1){
    int v = (t >= off) ? ps[t - off] : 0;
    __syncthreads();
    ps[t] += v;
    __syncthreads();
  }
  int base0 = (t == 0) ? 0 : ps[t - 1];
  arr[4 * t] = base0;
  arr[4 * t + 1] = base0 + v0;
  arr[4 * t + 2] = base0 + v0 + v1;
  arr[4 * t + 3] = base0 + v0 + v1 + v2;
  __syncthreads();
  for (int i = t; i < NB; i += 256) bpreT[b * NBPAD + i] = arr[i];
  if (t == 255) btot[b] = ps[255];
}

__global__ __launch_bounds__(256) void k_gscan(const int* __restrict__ btot,
                                               int* __restrict__ gstart, int nbuck,
                                               int* __restrict__ rp, int N, int E){
  __shared__ int sm[256];
  int t = threadIdx.x;
  sm[t] = (t < nbuck) ? btot[t] : 0;
  __syncthreads();
  for (int off = 1; off < 256; off <<= 1){
    int v = (t >= off) ? sm[t - off] : 0;
    __syncthreads();
    sm[t] += v;
    __syncthreads();
  }
  if (t < nbuck) gstart[t] = (t == 0) ? 0 : sm[t - 1];
  if (t == 0) rp[N] = E;
}

// stage tile's records bucket-grouped in LDS (computed positions), dump
// as coalesced bursts to bucket-contiguous tmp.
__global__ __launch_bounds__(256) void k_scatter(const int* __restrict__ src,
                                                 const int* __restrict__ dst, int E,
                                                 const int* __restrict__ bpreT,
                                                 const int* __restrict__ gstart,
                                                 unsigned* __restrict__ tmp){
  __shared__ unsigned srec[TILE];
  __shared__ unsigned char sbin[TILE];
  __shared__ int hist[256], scn[256], cur[256], lstart[256];
  int t = threadIdx.x, blk = blockIdx.x;
  hist[t] = 0; cur[t] = 0;
  __syncthreads();
  int base = blk * TILE;
#pragma unroll
  for (int k = 0; k < TILE / 256; ++k){
    int e = base + k * 256 + t;
    if (e < E) atomicAdd(&hist[dst[e] >> BSH], 1);
  }
  __syncthreads();
  scn[t] = hist[t];
  __syncthreads();
  for (int off = 1; off < 256; off <<= 1){
    int v = (t >= off) ? scn[t - off] : 0;
    __syncthreads();
    scn[t] += v;
    __syncthreads();
  }
  lstart[t] = (t == 0) ? 0 : scn[t - 1];
  __syncthreads();
#pragma unroll
  for (int k = 0; k < TILE / 256; ++k){
    int e = base + k * 256 + t;
    if (e < E){
      int d = dst[e], s = src[e], b = d >> BSH;
      int slot = atomicAdd(&cur[b], 1);
      int idx = lstart[b] + slot;
      srec[idx] = ((unsigned)(d & ((1 << BSH) - 1)) << 17) | (unsigned)s;
      sbin[idx] = (unsigned char)b;
    }
  }
  __syncthreads();
  int cntT = min(TILE, E - base);
#pragma unroll
  for (int k = 0; k < TILE / 256; ++k){
    int i = k * 256 + t;
    if (i < cntT){
      int b = sbin[i];
      int pos = gstart[b] + bpreT[b * NBPAD + blk] + (i - lstart[b]);
      tmp[pos] = srec[i];
    }
  }
}

// per bucket: deg hist + local scan -> rp/dinv; LDS scatter -> exact CSR; dump.
__global__ __launch_bounds__(256) void k_build(const unsigned* __restrict__ tmp,
                                               const int* __restrict__ gstart, int nbuck,
                                               int* __restrict__ rp,
                                               float* __restrict__ dinv,
                                               unsigned* __restrict__ col, int N, int E){
  __shared__ unsigned lcol[BCAP];
  __shared__ int deg[512], rpl[512], cur[512];
  __shared__ int ps[256];
  int b = blockIdx.x, t = threadIdx.x;
  int lo = b << BSH;
  int nn = min(512, N - lo);
  int gbase = gstart[b];
  int gend = (b + 1 < nbuck) ? gstart[b + 1] : E;
  int count = gend - gbase;
  for (int i = t; i < 512; i += 256){ deg[i] = 0; cur[i] = 0; }
  __syncthreads();
  const unsigned* trec = tmp + gbase;
  for (int i = t; i < count; i += 256) atomicAdd(&deg[trec[i] >> 17], 1);
  __syncthreads();
  int a0 = deg[2 * t], a1 = deg[2 * t + 1];
  ps[t] = a0 + a1;
  __syncthreads();
  for (int off = 1; off < 256; off <<= 1){
    int v = (t >= off) ? ps[t - off] : 0;
    __syncthreads();
    ps[t] += v;
    __syncthreads();
  }
  int excl = (t == 0) ? 0 : ps[t - 1];
  rpl[2 * t] = excl;
  rpl[2 * t + 1] = excl + a0;
  __syncthreads();
  for (int i = t; i < nn; i += 256){
    rp[lo + i] = gbase + rpl[i];
    dinv[lo + i] = rsqrtf((float)deg[i] + 1.0f);
  }
  if (count <= BCAP){
    for (int i = t; i < count; i += 256){
      unsigned r = trec[i];
      int d = r >> 17;
      int pos = rpl[d] + atomicAdd(&cur[d], 1);
      lcol[pos] = r & 0x1FFFFu;
    }
    __syncthreads();
    for (int i = t; i < count; i += 256) col[gbase + i] = lcol[i];
  } else {                                    // overflow fallback (never expected)
    for (int i = t; i < count; i += 256){
      unsigned r = trec[i];
      int d = r >> 17;
      int pos = rpl[d] + atomicAdd(&cur[d], 1);
      col[gbase + pos] = r & 0x1FFFFu;
    }
  }
}

// ---- weight prep: fp32 -> fp16 (RTN), bias sum -----------------------------
__global__ __launch_bounds__(256) void k_prep_w(const float* __restrict__ Wc,
                                                const float* __restrict__ Wr,
                                                const float* __restrict__ We,
                                                const float* __restrict__ bc,
                                                const float* __restrict__ br,
                                                _Float16* __restrict__ WcF,
                                                _Float16* __restrict__ WrF,
                                                _Float16* __restrict__ WeF,
                                                float* __restrict__ bias_sum){
  int i = blockIdx.x * 256 + threadIdx.x;
  if (i < HD * HD){
    WcF[i] = (_Float16)Wc[i];
    WrF[i] = (_Float16)Wr[i];
    WeF[i] = (_Float16)We[i];
  }
  if (i < HD) bias_sum[i] = bc[i] + br[i];
}

// ---- per-layer aggregation: U = dinv[dst] * sum_e dinv[src]*XsH[src] -------
// One wave per node. Quarter-wave per edge; lane gathers f16x8 (16B);
// 16 lanes * 16B = 256B row. 4x unroll => 16 gathers in flight per wave.
// r13: packed fp16 accumulate (v_pk_fma_f16) — 4 pk_fma/edge, f32 finish.
__global__ __launch_bounds__(256) void k_agg(const _Float16* __restrict__ XsH,
                                             const float* __restrict__ dinv,
                                             const int* __restrict__ rp,
                                             const unsigned* __restrict__ col,
                                             _Float16* __restrict__ U,
                                             int N){
  int w = threadIdx.x >> 6;
  int lane = threadIdx.x & 63;
  int q = lane >> 4;       // edge slot 0..3
  int ql = lane & 15;      // channel group: cols ql*8 .. ql*8+7
  int node = blockIdx.x * 4 + w;
  if (node >= N) return;

  f16x2 acc2[4];
#pragma unroll
  for (int k = 0; k < 4; ++k) acc2[k] = (f16x2)(_Float16)0;

  int b = rp[node], e = rp[node + 1];
  int j = b + q;
  for (; j + 12 < e; j += 16){
    unsigned c0 = col[j];
    unsigned c1 = col[j + 4];
    unsigned c2 = col[j + 8];
    unsigned c3 = col[j + 12];
    _Float16 h0 = (_Float16)dinv[c0];
    _Float16 h1 = (_Float16)dinv[c1];
    _Float16 h2 = (_Float16)dinv[c2];
    _Float16 h3 = (_Float16)dinv[c3];
    f16x8 v0 = ((const f16x8*)(XsH + (size_t)c0 * HD))[ql];
    f16x8 v1 = ((const f16x8*)(XsH + (size_t)c1 * HD))[ql];
    f16x8 v2 = ((const f16x8*)(XsH + (size_t)c2 * HD))[ql];
    f16x8 v3 = ((const f16x8*)(XsH + (size_t)c3 * HD))[ql];
    f16x2 w0; w0[0] = h0; w0[1] = h0;
    f16x2 w1; w1[0] = h1; w1[1] = h1;
    f16x2 w2; w2[0] = h2; w2[1] = h2;
    f16x2 w3; w3[0] = h3; w3[1] = h3;
    const f16x2* p0 = (const f16x2*)&v0;
    const f16x2* p1 = (const f16x2*)&v1;
    const f16x2* p2 = (const f16x2*)&v2;
    const f16x2* p3 = (const f16x2*)&v3;
#pragma unroll
    for (int k = 0; k < 4; ++k) acc2[k] += w0 * p0[k];
#pragma unroll
    for (int k = 0; k < 4; ++k) acc2[k] += w1 * p1[k];
#pragma unroll
    for (int k = 0; k < 4; ++k) acc2[k] += w2 * p2[k];
#pragma unroll
    for (int k = 0; k < 4; ++k) acc2[k] += w3 * p3[k];
  }
  for (; j < e; j += 4){
    unsigned c0 = col[j];
    _Float16 h0 = (_Float16)dinv[c0];
    f16x8 v0 = ((const f16x8*)(XsH + (size_t)c0 * HD))[ql];
    f16x2 w0; w0[0] = h0; w0[1] = h0;
    const f16x2* p0 = (const f16x2*)&v0;
#pragma unroll
    for (int k = 0; k < 4; ++k) acc2[k] += w0 * p0[k];
  }

  // f32 finish: cross-quarter reduce + dinv[dst] scale
  float acc[8];
#pragma unroll
  for (int k = 0; k < 4; ++k){
    acc[2 * k]     = (float)acc2[k][0];
    acc[2 * k + 1] = (float)acc2[k][1];
  }
  float dn = dinv[node];
#pragma unroll
  for (int i = 0; i < 8; ++i){
    acc[i] += __shfl_xor(acc[i], 16, 64);
    acc[i] += __shfl_xor(acc[i], 32, 64);
    acc[i] *= dn;
  }
  if (q == 0){
    f16x8 o;
#pragma unroll
    for (int i = 0; i < 8; ++i) o[i] = (_Float16)acc[i];
    ((f16x8*)(U + (size_t)node * HD))[ql] = o;
  }
}

// ---- fused fp16 GEMM, ONE weight matrix staged at a time (32KB LDS) --------
// two=false: out = cvt16(A1f) We^T + bias (encoder; A1f fp32).
// two=true:  pass A: acc += (U + (dinv^2-1)XsH) Wc^T; restage; pass B:
//            acc += XsH Wr^T; out = relu(acc + bias). Writes XsH fp16.
// decode: skip stores, val[row] = dot(out_row, Wd) + bd[0].
__global__ __launch_bounds__(256) void k_gemm(
    const float* __restrict__ A1f,            // encoder input x (fp32) or null
    const _Float16* __restrict__ A1h,         // U (fp16) or null
    const _Float16* A2h,                      // XsH (aliases outXsH) or null
    const _Float16* __restrict__ W1,          // WcF or WeF
    const _Float16* __restrict__ W2,          // WrF or null
    const float* __restrict__ dinvp,
    const float* __restrict__ bias,
    _Float16* outXsH,
    const float* __restrict__ Wd, const float* __restrict__ bd,
    float* __restrict__ val,
    int N, int relu, int decode){
  __shared__ _Float16 wsm[HD * HD];           // 32KB: [row][slot^]
  f16x8* smv = (f16x8*)wsm;
  int t = threadIdx.x;

  {
    const f16x8* g1 = (const f16x8*)W1;
    for (int i = t; i < HD * HD / 8; i += 256){
      int row = i >> 4, slot = i & 15;
      smv[(row << 4) | (slot ^ (row & 7))] = g1[i];
    }
  }
  __syncthreads();

  int wid = blockIdx.x * 4 + (t >> 6);
  int row0 = wid * 32;
  bool act = (row0 < N);
  int rowb = act ? row0 : 0;
  int lane = t & 63;
  int r = lane & 15;
  int kg = lane >> 4;

  f32x4 acc[2][8];
#pragma unroll
  for (int s = 0; s < 2; ++s)
#pragma unroll
    for (int c = 0; c < 8; ++c) acc[s][c] = (f32x4)0.0f;

  const bool two = (A2h != nullptr);
  float sr[2] = {0.f, 0.f};
  if (two){
#pragma unroll
    for (int s = 0; s < 2; ++s){
      float d = dinvp[rowb + s * 16 + r];
      sr[s] = d * d - 1.0f;
    }
  }

  // ---- pass A ----
#pragma unroll
  for (int kst = 0; kst < 4; ++kst){
    int k0 = kst * 32 + kg * 8;
    f16x8 a1[2];
#pragma unroll
    for (int s = 0; s < 2; ++s){
      size_t ao = (size_t)(rowb + s * 16 + r) * HD + k0;
      if (two){
        f16x8 uh = *(const f16x8*)(A1h + ao);
        f16x8 xv = *(const f16x8*)(A2h + ao);
#pragma unroll
        for (int i = 0; i < 8; ++i)
          a1[s][i] = (_Float16)fmaf(sr[s], (float)xv[i], (float)uh[i]);
      } else {
        f32x8 u = *(const f32x8*)(A1f + ao);
#pragma unroll
        for (int i = 0; i < 8; ++i) a1[s][i] = (_Float16)u[i];
      }
    }
    int swz = (kst * 4 + kg) ^ (r & 7);
#pragma unroll
    for (int ct = 0; ct < 8; ++ct){
      f16x8 b1 = smv[((ct * 16 + r) << 4) | swz];
#pragma unroll
      for (int s = 0; s < 2; ++s)
        acc[s][ct] = __builtin_amdgcn_mfma_f32_16x16x32_f16(a1[s], b1, acc[s][ct], 0, 0, 0);
    }
  }

  // ---- pass B ----
  if (two){
    __syncthreads();
    const f16x8* g2 = (const f16x8*)W2;
    for (int i = t; i < HD * HD / 8; i += 256){
      int row = i >> 4, slot = i & 15;
      smv[(row << 4) | (slot ^ (row & 7))] = g2[i];
    }
    __syncthreads();
#pragma unroll
    for (int kst = 0; kst < 4; ++kst){
      int k0 = kst * 32 + kg * 8;
      f16x8 a2[2];
#pragma unroll
      for (int s = 0; s < 2; ++s)
        a2[s] = *(const f16x8*)(A2h + (size_t)(rowb + s * 16 + r) * HD + k0);
      int swz = (kst * 4 + kg) ^ (r & 7);
#pragma unroll
      for (int ct = 0; ct < 8; ++ct){
        f16x8 b2 = smv[((ct * 16 + r) << 4) | swz];
#pragma unroll
        for (int s = 0; s < 2; ++s)
          acc[s][ct] = __builtin_amdgcn_mfma_f32_16x16x32_f16(a2[s], b2, acc[s][ct], 0, 0, 0);
      }
    }
  }

  // epilogue: C/D layout col = lane&15, row = kg*4 + reg
  float rowp[2][4] = {{0.f,0.f,0.f,0.f},{0.f,0.f,0.f,0.f}};
#pragma unroll
  for (int s = 0; s < 2; ++s){
#pragma unroll
    for (int ct = 0; ct < 8; ++ct){
      int cc = ct * 16 + r;
      float bv = bias[cc];
      float wdv = decode ? Wd[cc] : 0.f;
#pragma unroll
      for (int j = 0; j < 4; ++j){
        float v = acc[s][ct][j] + bv;
        if (relu) v = fmaxf(v, 0.0f);
        if (decode){
          rowp[s][j] += v * wdv;
        } else if (act){
          int rr = row0 + s * 16 + kg * 4 + j;
          outXsH[(size_t)rr * HD + cc] = (_Float16)v;
        }
      }
    }
  }
  if (decode && act){
    float bd0 = bd[0];
#pragma unroll
    for (int s = 0; s < 2; ++s)
#pragma unroll
      for (int j = 0; j < 4; ++j){
        float tt = rowp[s][j];
        tt += __shfl_xor(tt, 1, 64);
        tt += __shfl_xor(tt, 2, 64);
        tt += __shfl_xor(tt, 4, 64);
        tt += __shfl_xor(tt, 8, 64);
        if (r == 0) val[row0 + s * 16 + kg * 4 + j] = tt + bd0;
      }
  }
}

// ---- pooling: LDS histogram per block, few global atomics ------------------
#define POOL_CHUNK 1024
__global__ __launch_bounds__(256) void k_pool(const float* __restrict__ val,
                                              const int* __restrict__ batch,
                                              float* __restrict__ out, int N, int G){
  __shared__ float acc[4096];
  int t = threadIdx.x;
  int lo = blockIdx.x * POOL_CHUNK;
  int hi = min(lo + POOL_CHUNK, N);
  if (G <= 4096){
    for (int i = t; i < G; i += 256) acc[i] = 0.f;
    __syncthreads();
    for (int i = lo + t; i < hi; i += 256) atomicAdd(&acc[batch[i]], val[i]);
    __syncthreads();
    for (int i = t; i < G; i += 256){
      float v = acc[i];
      if (v != 0.f) atomicAdd(&out[i], v);
    }
  } else {
    for (int i = lo + t; i < hi; i += 256) atomicAdd(&out[batch[i]], val[i]);
  }
}

// ---- launcher ---------------------------------------------------------------
extern "C" void kernel_launch(void* const* d_in, const int* in_sizes, int n_in,
                              void* d_out, int out_size, void* d_ws, size_t ws_size,
                              hipStream_t stream){
  const float* x      = (const float*)d_in[0];
  const int*   ei     = (const int*)d_in[1];
  const int*   batch  = (const int*)d_in[2];
  const float* W_enc  = (const float*)d_in[3];
  const float* b_enc  = (const float*)d_in[4];
  const float* W_conv = (const float*)d_in[5];
  const float* b_conv = (const float*)d_in[6];
  const float* W_res  = (const float*)d_in[7];
  const float* b_res  = (const float*)d_in[8];
  const float* W_dec  = (const float*)d_in[9];
  const float* b_dec  = (const float*)d_in[10];

  const int N = in_sizes[0] / HD;
  const int E = in_sizes[1] / 2;
  const int NB = (E + TILE - 1) / TILE;            // <= NBPAD
  const int nbuck = (N + (1 << BSH) - 1) >> BSH;   // <= 256
  float* out = (float*)d_out;

  char* ws = (char*)d_ws;
  size_t off = 0;
  auto alloc = [&](size_t bytes) -> char* {
    char* p = ws + off;
    off += (bytes + 255) & ~(size_t)255;
    return p;
  };
  int*   rp    = (int*)  alloc(((size_t)N + 1) * 4);
  float* dinv  = (float*)alloc((size_t)N * 4);
  int*   bcnt  = (int*)  alloc((size_t)NBPAD * 256 * 4);
  int*   bpreT = (int*)  alloc((size_t)256 * NBPAD * 4);
  int*   btot  = (int*)  alloc(256 * 4);
  int*   gstart= (int*)  alloc(256 * 4);
  unsigned* tmp= (unsigned*)alloc((size_t)E * 4);
  unsigned* col= (unsigned*)alloc((size_t)E * 4);
  _Float16* XsH= (_Float16*)alloc((size_t)N * HD * 2);
  _Float16* U  = (_Float16*)alloc((size_t)N * HD * 2);
  float* val   = (float*)alloc((size_t)N * 4);
  _Float16* WcF = (_Float16*)alloc((size_t)HD * HD * 2);
  _Float16* WrF = (_Float16*)alloc((size_t)HD * HD * 2);
  _Float16* WeF = (_Float16*)alloc((size_t)HD * HD * 2);
  float* bias_sum = (float*)alloc((size_t)HD * 4);

  hipMemsetAsync(out, 0, (size_t)out_size * 4, stream);

  const int* src = ei;
  const int* dst = ei + E;

  k_count  <<<NB, 256, 0, stream>>>(dst, E, bcnt);
  k_btot   <<<nbuck, 256, 0, stream>>>(bcnt, bpreT, btot, NB);
  k_gscan  <<<1, 256, 0, stream>>>(btot, gstart, nbuck, rp, N, E);
  k_scatter<<<NB, 256, 0, stream>>>(src, dst, E, bpreT, gstart, tmp);
  k_build  <<<nbuck, 256, 0, stream>>>(tmp, gstart, nbuck, rp, dinv, col, N, E);
  k_prep_w <<<(HD * HD + 255) / 256, 256, 0, stream>>>(W_conv, W_res, W_enc, b_conv, b_res,
                                                       WcF, WrF, WeF, bias_sum);

  int gemm_blocks = ((N + 31) / 32 + 3) / 4;
  int node_blocks = (N + 3) / 4;

  // encoder: XsH = fp16(x @ W_enc^T + b_enc)
  k_gemm<<<gemm_blocks, 256, 0, stream>>>(x, nullptr, nullptr, WeF, nullptr,
                                          nullptr, b_enc, XsH,
                                          nullptr, nullptr, nullptr, N, 0, 0);

  for (int l = 0; l < 5; ++l){
    k_agg<<<node_blocks, 256, 0, stream>>>(XsH, dinv, rp, col, U, N);
    int last = (l == 4);
    k_gemm<<<gemm_blocks, 256, 0, stream>>>(nullptr, U, XsH, WcF, WrF,
                                            dinv, bias_sum, XsH,
                                            W_dec, b_dec, val, N, 1, last);
  }

  k_pool<<<(N + POOL_CHUNK - 1) / POOL_CHUNK, 256, 0, stream>>>(val, batch, out, N, out_size);
}

// Round 14
// 542.321 us; speedup vs baseline: 2.0502x; 1.0058x over previous
//
#include <hip/hip_runtime.h>
#include <hip/hip_bf16.h>
#include <stdint.h>

// GraphCON-GCN on MI355X.
// Algebra: with DT=ALPHA=GAMMA=1, Xs_{l+1} = relu(gcn+res); Y drops out.
// z = (A.Xs) Wc^T + (dinv^2-1) Xs Wc^T + Xs Wr^T + (b_c+b_r).
// r14: state stored PRE-SCALED X' = dinv*X (fp16). Gather becomes pure
// unweighted sum of X'[src] rows (no per-edge dinv load, no weight math);
// dinv[dst] applied post-reduce. GEMM reconstructs raw operands per-row:
// A1 = U + ((d^2-1)/d) X' (pk_fma), A2 = (1/d) X' (pk_mul); epilogue stores
// dinv*v. CSR build = tile multisplit (r12). Decode fused into final GEMM;
// pooling via LDS histogram.

#define HD 128
#define BSH 9                 // bucket = 512 nodes
#define TILE 4096             // edges per multisplit tile
#define NBPAD 1024            // max tiles (E <= 4M)
#define BCAP 10240            // k_build LDS col capacity (40KB)

typedef __attribute__((ext_vector_type(4))) float f32x4;
typedef __attribute__((ext_vector_type(8))) float f32x8;
typedef __attribute__((ext_vector_type(8))) _Float16 f16x8;
typedef __attribute__((ext_vector_type(2))) _Float16 f16x2;

// ---- CSR build: tile multisplit -------------------------------------------
__global__ __launch_bounds__(256) void k_count(const int* __restrict__ dst, int E,
                                               int* __restrict__ bcnt){
  __shared__ int hist[256];
  int t = threadIdx.x;
  hist[t] = 0;
  __syncthreads();
  int base = blockIdx.x * TILE;
#pragma unroll
  for (int k = 0; k < TILE / 256; ++k){
    int e = base + k * 256 + t;
    if (e < E) atomicAdd(&hist[dst[e] >> BSH], 1);
  }
  __syncthreads();
  bcnt[blockIdx.x * 256 + t] = hist[t];
}

// one block per bucket: exclusive prefix of its column over tiles
__global__ __launch_bounds__(256) void k_btot(const int* __restrict__ bcnt,
                                              int* __restrict__ bpreT,
                                              int* __restrict__ btot, int NB){
  __shared__ int arr[NBPAD];
  __shared__ int ps[256];
  int b = blockIdx.x, t = threadIdx.x;
  for (int i = t; i < NBPAD; i += 256) arr[i] = (i < NB) ? bcnt[i * 256 + b] : 0;
  __syncthreads();
  int v0 = arr[4 * t], v1 = arr[4 * t + 1], v2 = arr[4 * t + 2], v3 = arr[4 * t + 3];
  ps[t] = v0 + v1 + v2 + v3;
  __syncthreads();
  for (int off = 1; off < 256; off <<= 1){
    int v = (t >= off) ? ps[t - off] : 0;
    __syncthreads();
    ps[t] += v;
    __syncthreads();
  }
  int base0 = (t == 0) ? 0 : ps[t - 1];
  arr[4 * t] = base0;
  arr[4 * t + 1] = base0 + v0;
  arr[4 * t + 2] = base0 + v0 + v1;
  arr[4 * t + 3] = base0 + v0 + v1 + v2;
  __syncthreads();
  for (int i = t; i < NB; i += 256) bpreT[b * NBPAD + i] = arr[i];
  if (t == 255) btot[b] = ps[255];
}

__global__ __launch_bounds__(256) void k_gscan(const int* __restrict__ btot,
                                               int* __restrict__ gstart, int nbuck,
                                               int* __restrict__ rp, int N, int E){
  __shared__ int sm[256];
  int t = threadIdx.x;
  sm[t] = (t < nbuck) ? btot[t] : 0;
  __syncthreads();
  for (int off = 1; off < 256; off <<= 1){
    int v = (t >= off) ? sm[t - off] : 0;
    __syncthreads();
    sm[t] += v;
    __syncthreads();
  }
  if (t < nbuck) gstart[t] = (t == 0) ? 0 : sm[t - 1];
  if (t == 0) rp[N] = E;
}

// stage tile's records bucket-grouped in LDS (computed positions), dump
// as coalesced bursts to bucket-contiguous tmp.
__global__ __launch_bounds__(256) void k_scatter(const int* __restrict__ src,
                                                 const int* __restrict__ dst, int E,
                                                 const int* __restrict__ bpreT,
                                                 const int* __restrict__ gstart,
                                                 unsigned* __restrict__ tmp){
  __shared__ unsigned srec[TILE];
  __shared__ unsigned char sbin[TILE];
  __shared__ int hist[256], scn[256], cur[256], lstart[256];
  int t = threadIdx.x, blk = blockIdx.x;
  hist[t] = 0; cur[t] = 0;
  __syncthreads();
  int base = blk * TILE;
#pragma unroll
  for (int k = 0; k < TILE / 256; ++k){
    int e = base + k * 256 + t;
    if (e < E) atomicAdd(&hist[dst[e] >> BSH], 1);
  }
  __syncthreads();
  scn[t] = hist[t];
  __syncthreads();
  for (int off = 1; off < 256; off <<= 1){
    int v = (t >= off) ? scn[t - off] : 0;
    __syncthreads();
    scn[t] += v;
    __syncthreads();
  }
  lstart[t] = (t == 0) ? 0 : scn[t - 1];
  __syncthreads();
#pragma unroll
  for (int k = 0; k < TILE / 256; ++k){
    int e = base + k * 256 + t;
    if (e < E){
      int d = dst[e], s = src[e], b = d >> BSH;
      int slot = atomicAdd(&cur[b], 1);
      int idx = lstart[b] + slot;
      srec[idx] = ((unsigned)(d & ((1 << BSH) - 1)) << 17) | (unsigned)s;
      sbin[idx] = (unsigned char)b;
    }
  }
  __syncthreads();
  int cntT = min(TILE, E - base);
#pragma unroll
  for (int k = 0; k < TILE / 256; ++k){
    int i = k * 256 + t;
    if (i < cntT){
      int b = sbin[i];
      int pos = gstart[b] + bpreT[b * NBPAD + blk] + (i - lstart[b]);
      tmp[pos] = srec[i];
    }
  }
}

// per bucket: deg hist + local scan -> rp/dinv; LDS scatter -> exact CSR; dump.
__global__ __launch_bounds__(256) void k_build(const unsigned* __restrict__ tmp,
                                               const int* __restrict__ gstart, int nbuck,
                                               int* __restrict__ rp,
                                               float* __restrict__ dinv,
                                               unsigned* __restrict__ col, int N, int E){
  __shared__ unsigned lcol[BCAP];
  __shared__ int deg[512], rpl[512], cur[512];
  __shared__ int ps[256];
  int b = blockIdx.x, t = threadIdx.x;
  int lo = b << BSH;
  int nn = min(512, N - lo);
  int gbase = gstart[b];
  int gend = (b + 1 < nbuck) ? gstart[b + 1] : E;
  int count = gend - gbase;
  for (int i = t; i < 512; i += 256){ deg[i] = 0; cur[i] = 0; }
  __syncthreads();
  const unsigned* trec = tmp + gbase;
  for (int i = t; i < count; i += 256) atomicAdd(&deg[trec[i] >> 17], 1);
  __syncthreads();
  int a0 = deg[2 * t], a1 = deg[2 * t + 1];
  ps[t] = a0 + a1;
  __syncthreads();
  for (int off = 1; off < 256; off <<= 1){
    int v = (t >= off) ? ps[t - off] : 0;
    __syncthreads();
    ps[t] += v;
    __syncthreads();
  }
  int excl = (t == 0) ? 0 : ps[t - 1];
  rpl[2 * t] = excl;
  rpl[2 * t + 1] = excl + a0;
  __syncthreads();
  for (int i = t; i < nn; i += 256){
    rp[lo + i] = gbase + rpl[i];
    dinv[lo + i] = rsqrtf((float)deg[i] + 1.0f);
  }
  if (count <= BCAP){
    for (int i = t; i < count; i += 256){
      unsigned r = trec[i];
      int d = r >> 17;
      int pos = rpl[d] + atomicAdd(&cur[d], 1);
      lcol[pos] = r & 0x1FFFFu;
    }
    __syncthreads();
    for (int i = t; i < count; i += 256) col[gbase + i] = lcol[i];
  } else {                                    // overflow fallback (never expected)
    for (int i = t; i < count; i += 256){
      unsigned r = trec[i];
      int d = r >> 17;
      int pos = rpl[d] + atomicAdd(&cur[d], 1);
      col[gbase + pos] = r & 0x1FFFFu;
    }
  }
}

// ---- weight prep: fp32 -> fp16 (RTN), bias sum -----------------------------
__global__ __launch_bounds__(256) void k_prep_w(const float* __restrict__ Wc,
                                                const float* __restrict__ Wr,
                                                const float* __restrict__ We,
                                                const float* __restrict__ bc,
                                                const float* __restrict__ br,
                                                _Float16* __restrict__ WcF,
                                                _Float16* __restrict__ WrF,
                                                _Float16* __restrict__ WeF,
                                                float* __restrict__ bias_sum){
  int i = blockIdx.x * 256 + threadIdx.x;
  if (i < HD * HD){
    WcF[i] = (_Float16)Wc[i];
    WrF[i] = (_Float16)Wr[i];
    WeF[i] = (_Float16)We[i];
  }
  if (i < HD) bias_sum[i] = bc[i] + br[i];
}

// ---- per-layer aggregation: U[d] = dinv[d] * sum_e X'[src]  (X' pre-scaled)-
// One wave per node. Quarter-wave per edge; lane gathers f16x8 (16B);
// 16 lanes * 16B = 256B row. 4x unroll => 16 gathers in flight per wave.
// Inner loop: 1 gather + 4 pk_add per edge — no weight loads, no weight math.
__global__ __launch_bounds__(256) void k_agg(const _Float16* __restrict__ XsH,
                                             const float* __restrict__ dinv,
                                             const int* __restrict__ rp,
                                             const unsigned* __restrict__ col,
                                             _Float16* __restrict__ U,
                                             int N){
  int w = threadIdx.x >> 6;
  int lane = threadIdx.x & 63;
  int q = lane >> 4;       // edge slot 0..3
  int ql = lane & 15;      // channel group: cols ql*8 .. ql*8+7
  int node = blockIdx.x * 4 + w;
  if (node >= N) return;

  f16x2 acc2[4];
#pragma unroll
  for (int k = 0; k < 4; ++k) acc2[k] = (f16x2)(_Float16)0;

  int b = rp[node], e = rp[node + 1];
  int j = b + q;
  for (; j + 12 < e; j += 16){
    unsigned c0 = col[j];
    unsigned c1 = col[j + 4];
    unsigned c2 = col[j + 8];
    unsigned c3 = col[j + 12];
    f16x8 v0 = ((const f16x8*)(XsH + (size_t)c0 * HD))[ql];
    f16x8 v1 = ((const f16x8*)(XsH + (size_t)c1 * HD))[ql];
    f16x8 v2 = ((const f16x8*)(XsH + (size_t)c2 * HD))[ql];
    f16x8 v3 = ((const f16x8*)(XsH + (size_t)c3 * HD))[ql];
    const f16x2* p0 = (const f16x2*)&v0;
    const f16x2* p1 = (const f16x2*)&v1;
    const f16x2* p2 = (const f16x2*)&v2;
    const f16x2* p3 = (const f16x2*)&v3;
#pragma unroll
    for (int k = 0; k < 4; ++k) acc2[k] += p0[k];
#pragma unroll
    for (int k = 0; k < 4; ++k) acc2[k] += p1[k];
#pragma unroll
    for (int k = 0; k < 4; ++k) acc2[k] += p2[k];
#pragma unroll
    for (int k = 0; k < 4; ++k) acc2[k] += p3[k];
  }
  for (; j < e; j += 4){
    unsigned c0 = col[j];
    f16x8 v0 = ((const f16x8*)(XsH + (size_t)c0 * HD))[ql];
    const f16x2* p0 = (const f16x2*)&v0;
#pragma unroll
    for (int k = 0; k < 4; ++k) acc2[k] += p0[k];
  }

  // f32 finish: cross-quarter reduce + dinv[dst] scale
  float acc[8];
#pragma unroll
  for (int k = 0; k < 4; ++k){
    acc[2 * k]     = (float)acc2[k][0];
    acc[2 * k + 1] = (float)acc2[k][1];
  }
  float dn = dinv[node];
#pragma unroll
  for (int i = 0; i < 8; ++i){
    acc[i] += __shfl_xor(acc[i], 16, 64);
    acc[i] += __shfl_xor(acc[i], 32, 64);
    acc[i] *= dn;
  }
  if (q == 0){
    f16x8 o;
#pragma unroll
    for (int i = 0; i < 8; ++i) o[i] = (_Float16)acc[i];
    ((f16x8*)(U + (size_t)node * HD))[ql] = o;
  }
}

// ---- fused fp16 GEMM, ONE weight matrix staged at a time (32KB LDS) --------
// State array A2h holds X' = dinv*X. Raw operands rebuilt per-row:
//   pass A: a1 = U + ((d^2-1)/d) X'  (pk_fma);  pass B: a2 = (1/d) X' (pk_mul)
// Output store: X'new = dinv[row] * relu(acc+bias).
// two=false (encoder): a1 = cvt16(x fp32); store scaled.
// decode: skip stores, val[row] = dot(raw out_row, Wd) + bd[0].
__global__ __launch_bounds__(256) void k_gemm(
    const float* __restrict__ A1f,            // encoder input x (fp32) or null
    const _Float16* __restrict__ A1h,         // U (fp16) or null
    const _Float16* A2h,                      // X' (aliases outXsH) or null
    const _Float16* __restrict__ W1,          // WcF or WeF
    const _Float16* __restrict__ W2,          // WrF or null
    const float* __restrict__ dinvp,
    const float* __restrict__ bias,
    _Float16* outXsH,
    const float* __restrict__ Wd, const float* __restrict__ bd,
    float* __restrict__ val,
    int N, int relu, int decode){
  __shared__ _Float16 wsm[HD * HD];           // 32KB: [row][slot^]
  f16x8* smv = (f16x8*)wsm;
  int t = threadIdx.x;

  {
    const f16x8* g1 = (const f16x8*)W1;
    for (int i = t; i < HD * HD / 8; i += 256){
      int row = i >> 4, slot = i & 15;
      smv[(row << 4) | (slot ^ (row & 7))] = g1[i];
    }
  }
  __syncthreads();

  int wid = blockIdx.x * 4 + (t >> 6);
  int row0 = wid * 32;
  bool act = (row0 < N);
  int rowb = act ? row0 : 0;
  int lane = t & 63;
  int r = lane & 15;
  int kg = lane >> 4;

  f32x4 acc[2][8];
#pragma unroll
  for (int s = 0; s < 2; ++s)
#pragma unroll
    for (int c = 0; c < 8; ++c) acc[s][c] = (f32x4)0.0f;

  const bool two = (A2h != nullptr);
  f16x2 srA2[2], srB2[2];
  if (two){
#pragma unroll
    for (int s = 0; s < 2; ++s){
      float d = dinvp[rowb + s * 16 + r];
      float rd = 1.0f / d;
      _Float16 ha = (_Float16)((d * d - 1.0f) * rd);
      _Float16 hb = (_Float16)rd;
      srA2[s][0] = ha; srA2[s][1] = ha;
      srB2[s][0] = hb; srB2[s][1] = hb;
    }
  }

  // ---- pass A ----
#pragma unroll
  for (int kst = 0; kst < 4; ++kst){
    int k0 = kst * 32 + kg * 8;
    f16x8 a1[2];
#pragma unroll
    for (int s = 0; s < 2; ++s){
      size_t ao = (size_t)(rowb + s * 16 + r) * HD + k0;
      if (two){
        f16x8 uh = *(const f16x8*)(A1h + ao);
        f16x8 xv = *(const f16x8*)(A2h + ao);
        f16x2* a1p = (f16x2*)&a1[s];
        const f16x2* up = (const f16x2*)&uh;
        const f16x2* xp = (const f16x2*)&xv;
#pragma unroll
        for (int k = 0; k < 4; ++k) a1p[k] = up[k] + srA2[s] * xp[k];
      } else {
        f32x8 u = *(const f32x8*)(A1f + ao);
#pragma unroll
        for (int i = 0; i < 8; ++i) a1[s][i] = (_Float16)u[i];
      }
    }
    int swz = (kst * 4 + kg) ^ (r & 7);
#pragma unroll
    for (int ct = 0; ct < 8; ++ct){
      f16x8 b1 = smv[((ct * 16 + r) << 4) | swz];
#pragma unroll
      for (int s = 0; s < 2; ++s)
        acc[s][ct] = __builtin_amdgcn_mfma_f32_16x16x32_f16(a1[s], b1, acc[s][ct], 0, 0, 0);
    }
  }

  // ---- pass B ----
  if (two){
    __syncthreads();
    const f16x8* g2 = (const f16x8*)W2;
    for (int i = t; i < HD * HD / 8; i += 256){
      int row = i >> 4, slot = i & 15;
      smv[(row << 4) | (slot ^ (row & 7))] = g2[i];
    }
    __syncthreads();
#pragma unroll
    for (int kst = 0; kst < 4; ++kst){
      int k0 = kst * 32 + kg * 8;
      f16x8 a2[2];
#pragma unroll
      for (int s = 0; s < 2; ++s){
        f16x8 xv = *(const f16x8*)(A2h + (size_t)(rowb + s * 16 + r) * HD + k0);
        f16x2* a2p = (f16x2*)&a2[s];
        const f16x2* xp = (const f16x2*)&xv;
#pragma unroll
        for (int k = 0; k < 4; ++k) a2p[k] = srB2[s] * xp[k];
      }
      int swz = (kst * 4 + kg) ^ (r & 7);
#pragma unroll
      for (int ct = 0; ct < 8; ++ct){
        f16x8 b2 = smv[((ct * 16 + r) << 4) | swz];
#pragma unroll
        for (int s = 0; s < 2; ++s)
          acc[s][ct] = __builtin_amdgcn_mfma_f32_16x16x32_f16(a2[s], b2, acc[s][ct], 0, 0, 0);
      }
    }
  }

  // epilogue: C/D layout col = lane&15, row = kg*4 + reg
  float dout[2][4];
  if (act && !decode){
#pragma unroll
    for (int s = 0; s < 2; ++s)
#pragma unroll
      for (int j = 0; j < 4; ++j)
        dout[s][j] = dinvp[row0 + s * 16 + kg * 4 + j];
  }
  float rowp[2][4] = {{0.f,0.f,0.f,0.f},{0.f,0.f,0.f,0.f}};
#pragma unroll
  for (int s = 0; s < 2; ++s){
#pragma unroll
    for (int ct = 0; ct < 8; ++ct){
      int cc = ct * 16 + r;
      float bv = bias[cc];
      float wdv = decode ? Wd[cc] : 0.f;
#pragma unroll
      for (int j = 0; j < 4; ++j){
        float v = acc[s][ct][j] + bv;
        if (relu) v = fmaxf(v, 0.0f);
        if (decode){
          rowp[s][j] += v * wdv;
        } else if (act){
          int rr = row0 + s * 16 + kg * 4 + j;
          outXsH[(size_t)rr * HD + cc] = (_Float16)(dout[s][j] * v);
        }
      }
    }
  }
  if (decode && act){
    float bd0 = bd[0];
#pragma unroll
    for (int s = 0; s < 2; ++s)
#pragma unroll
      for (int j = 0; j < 4; ++j){
        float tt = rowp[s][j];
        tt += __shfl_xor(tt, 1, 64);
        tt += __shfl_xor(tt, 2, 64);
        tt += __shfl_xor(tt, 4, 64);
        tt += __shfl_xor(tt, 8, 64);
        if (r == 0) val[row0 + s * 16 + kg * 4 + j] = tt + bd0;
      }
  }
}

// ---- pooling: LDS histogram per block, few global atomics ------------------
#define POOL_CHUNK 1024
__global__ __launch_bounds__(256) void k_pool(const float* __restrict__ val,
                                              const int* __restrict__ batch,
                                              float* __restrict__ out, int N, int G){
  __shared__ float acc[4096];
  int t = threadIdx.x;
  int lo = blockIdx.x * POOL_CHUNK;
  int hi = min(lo + POOL_CHUNK, N);
  if (G <= 4096){
    for (int i = t; i < G; i += 256) acc[i] = 0.f;
    __syncthreads();
    for (int i = lo + t; i < hi; i += 256) atomicAdd(&acc[batch[i]], val[i]);
    __syncthreads();
    for (int i = t; i < G; i += 256){
      float v = acc[i];
      if (v != 0.f) atomicAdd(&out[i], v);
    }
  } else {
    for (int i = lo + t; i < hi; i += 256) atomicAdd(&out[batch[i]], val[i]);
  }
}

// ---- launcher ---------------------------------------------------------------
extern "C" void kernel_launch(void* const* d_in, const int* in_sizes, int n_in,
                              void* d_out, int out_size, void* d_ws, size_t ws_size,
                              hipStream_t stream){
  const float* x      = (const float*)d_in[0];
  const int*   ei     = (const int*)d_in[1];
  const int*   batch  = (const int*)d_in[2];
  const float* W_enc  = (const float*)d_in[3];
  const float* b_enc  = (const float*)d_in[4];
  const float* W_conv = (const float*)d_in[5];
  const float* b_conv = (const float*)d_in[6];
  const float* W_res  = (const float*)d_in[7];
  const float* b_res  = (const float*)d_in[8];
  const float* W_dec  = (const float*)d_in[9];
  const float* b_dec  = (const float*)d_in[10];

  const int N = in_sizes[0] / HD;
  const int E = in_sizes[1] / 2;
  const int NB = (E + TILE - 1) / TILE;            // <= NBPAD
  const int nbuck = (N + (1 << BSH) - 1) >> BSH;   // <= 256
  float* out = (float*)d_out;

  char* ws = (char*)d_ws;
  size_t off = 0;
  auto alloc = [&](size_t bytes) -> char* {
    char* p = ws + off;
    off += (bytes + 255) & ~(size_t)255;
    return p;
  };
  int*   rp    = (int*)  alloc(((size_t)N + 1) * 4);
  float* dinv  = (float*)alloc((size_t)N * 4);
  int*   bcnt  = (int*)  alloc((size_t)NBPAD * 256 * 4);
  int*   bpreT = (int*)  alloc((size_t)256 * NBPAD * 4);
  int*   btot  = (int*)  alloc(256 * 4);
  int*   gstart= (int*)  alloc(256 * 4);
  unsigned* tmp= (unsigned*)alloc((size_t)E * 4);
  unsigned* col= (unsigned*)alloc((size_t)E * 4);
  _Float16* XsH= (_Float16*)alloc((size_t)N * HD * 2);
  _Float16* U  = (_Float16*)alloc((size_t)N * HD * 2);
  float* val   = (float*)alloc((size_t)N * 4);
  _Float16* WcF = (_Float16*)alloc((size_t)HD * HD * 2);
  _Float16* WrF = (_Float16*)alloc((size_t)HD * HD * 2);
  _Float16* WeF = (_Float16*)alloc((size_t)HD * HD * 2);
  float* bias_sum = (float*)alloc((size_t)HD * 4);

  hipMemsetAsync(out, 0, (size_t)out_size * 4, stream);

  const int* src = ei;
  const int* dst = ei + E;

  k_count  <<<NB, 256, 0, stream>>>(dst, E, bcnt);
  k_btot   <<<nbuck, 256, 0, stream>>>(bcnt, bpreT, btot, NB);
  k_gscan  <<<1, 256, 0, stream>>>(btot, gstart, nbuck, rp, N, E);
  k_scatter<<<NB, 256, 0, stream>>>(src, dst, E, bpreT, gstart, tmp);
  k_build  <<<nbuck, 256, 0, stream>>>(tmp, gstart, nbuck, rp, dinv, col, N, E);
  k_prep_w <<<(HD * HD + 255) / 256, 256, 0, stream>>>(W_conv, W_res, W_enc, b_conv, b_res,
                                                       WcF, WrF, WeF, bias_sum);

  int gemm_blocks = ((N + 31) / 32 + 3) / 4;
  int node_blocks = (N + 3) / 4;

  // encoder: XsH = dinv * fp16(x @ W_enc^T + b_enc)   (pre-scaled state)
  k_gemm<<<gemm_blocks, 256, 0, stream>>>(x, nullptr, nullptr, WeF, nullptr,
                                          dinv, b_enc, XsH,
                                          nullptr, nullptr, nullptr, N, 0, 0);

  for (int l = 0; l < 5; ++l){
    k_agg<<<node_blocks, 256, 0, stream>>>(XsH, dinv, rp, col, U, N);
    int last = (l == 4);
    k_gemm<<<gemm_blocks, 256, 0, stream>>>(nullptr, U, XsH, WcF, WrF,
                                            dinv, bias_sum, XsH,
                                            W_dec, b_dec, val, N, 1, last);
  }

  k_pool<<<(N + POOL_CHUNK - 1) / POOL_CHUNK, 256, 0, stream>>>(val, batch, out, N, out_size);
}

// Round 15
// 533.939 us; speedup vs baseline: 2.0824x; 1.0157x over previous
//
#include <hip/hip_runtime.h>
#include <hip/hip_bf16.h>
#include <stdint.h>

// GraphCON-GCN on MI355X.
// Algebra: with DT=ALPHA=GAMMA=1, Xs_{l+1} = relu(gcn+res); Y drops out.
// z = (A.Xs) Wc^T + (dinv^2-1) Xs Wc^T + Xs Wr^T + (b_c+b_r).
// State stored PRE-SCALED X' = dinv*X (fp16): gather = pure unweighted sum
// (1 gather + 4 pk_add per edge), dinv[dst] post-reduce. k_agg is at the
// L1-transaction floor (4 lines/edge, 3 micro-opts all <3%).
// GEMM rebuilds raw operands per-row: A1 = U + ((d^2-1)/d) X', A2 = (1/d) X';
// r15: X' register-cached across passes (32 VGPR) — pass B does no global
// reads; per-layer GEMM traffic 102 -> 77 MB.
// CSR build = tile multisplit (r12). Decode fused into final GEMM;
// pooling via LDS histogram.

#define HD 128
#define BSH 9                 // bucket = 512 nodes
#define TILE 4096             // edges per multisplit tile
#define NBPAD 1024            // max tiles (E <= 4M)
#define BCAP 10240            // k_build LDS col capacity (40KB)

typedef __attribute__((ext_vector_type(4))) float f32x4;
typedef __attribute__((ext_vector_type(8))) float f32x8;
typedef __attribute__((ext_vector_type(8))) _Float16 f16x8;
typedef __attribute__((ext_vector_type(2))) _Float16 f16x2;

// ---- CSR build: tile multisplit -------------------------------------------
__global__ __launch_bounds__(256) void k_count(const int* __restrict__ dst, int E,
                                               int* __restrict__ bcnt){
  __shared__ int hist[256];
  int t = threadIdx.x;
  hist[t] = 0;
  __syncthreads();
  int base = blockIdx.x * TILE;
#pragma unroll
  for (int k = 0; k < TILE / 256; ++k){
    int e = base + k * 256 + t;
    if (e < E) atomicAdd(&hist[dst[e] >> BSH], 1);
  }
  __syncthreads();
  bcnt[blockIdx.x * 256 + t] = hist[t];
}

// one block per bucket: exclusive prefix of its column over tiles
__global__ __launch_bounds__(256) void k_btot(const int* __restrict__ bcnt,
                                              int* __restrict__ bpreT,
                                              int* __restrict__ btot, int NB){
  __shared__ int arr[NBPAD];
  __shared__ int ps[256];
  int b = blockIdx.x, t = threadIdx.x;
  for (int i = t; i < NBPAD; i += 256) arr[i] = (i < NB) ? bcnt[i * 256 + b] : 0;
  __syncthreads();
  int v0 = arr[4 * t], v1 = arr[4 * t + 1], v2 = arr[4 * t + 2], v3 = arr[4 * t + 3];
  ps[t] = v0 + v1 + v2 + v3;
  __syncthreads();
  for (int off = 1; off < 256; off <<= 1){
    int v = (t >= off) ? ps[t - off] : 0;
    __syncthreads();
    ps[t] += v;
    __syncthreads();
  }
  int base0 = (t == 0) ? 0 : ps[t - 1];
  arr[4 * t] = base0;
  arr[4 * t + 1] = base0 + v0;
  arr[4 * t + 2] = base0 + v0 + v1;
  arr[4 * t + 3] = base0 + v0 + v1 + v2;
  __syncthreads();
  for (int i = t; i < NB; i += 256) bpreT[b * NBPAD + i] = arr[i];
  if (t == 255) btot[b] = ps[255];
}

__global__ __launch_bounds__(256) void k_gscan(const int* __restrict__ btot,
                                               int* __restrict__ gstart, int nbuck,
                                               int* __restrict__ rp, int N, int E){
  __shared__ int sm[256];
  int t = threadIdx.x;
  sm[t] = (t < nbuck) ? btot[t] : 0;
  __syncthreads();
  for (int off = 1; off < 256; off <<= 1){
    int v = (t >= off) ? sm[t - off] : 0;
    __syncthreads();
    sm[t] += v;
    __syncthreads();
  }
  if (t < nbuck) gstart[t] = (t == 0) ? 0 : sm[t - 1];
  if (t == 0) rp[N] = E;
}

// stage tile's records bucket-grouped in LDS (computed positions), dump
// as coalesced bursts to bucket-contiguous tmp.
__global__ __launch_bounds__(256) void k_scatter(const int* __restrict__ src,
                                                 const int* __restrict__ dst, int E,
                                                 const int* __restrict__ bpreT,
                                                 const int* __restrict__ gstart,
                                                 unsigned* __restrict__ tmp){
  __shared__ unsigned srec[TILE];
  __shared__ unsigned char sbin[TILE];
  __shared__ int hist[256], scn[256], cur[256], lstart[256];
  int t = threadIdx.x, blk = blockIdx.x;
  hist[t] = 0; cur[t] = 0;
  __syncthreads();
  int base = blk * TILE;
#pragma unroll
  for (int k = 0; k < TILE / 256; ++k){
    int e = base + k * 256 + t;
    if (e < E) atomicAdd(&hist[dst[e] >> BSH], 1);
  }
  __syncthreads();
  scn[t] = hist[t];
  __syncthreads();
  for (int off = 1; off < 256; off <<= 1){
    int v = (t >= off) ? scn[t - off] : 0;
    __syncthreads();
    scn[t] += v;
    __syncthreads();
  }
  lstart[t] = (t == 0) ? 0 : scn[t - 1];
  __syncthreads();
#pragma unroll
  for (int k = 0; k < TILE / 256; ++k){
    int e = base + k * 256 + t;
    if (e < E){
      int d = dst[e], s = src[e], b = d >> BSH;
      int slot = atomicAdd(&cur[b], 1);
      int idx = lstart[b] + slot;
      srec[idx] = ((unsigned)(d & ((1 << BSH) - 1)) << 17) | (unsigned)s;
      sbin[idx] = (unsigned char)b;
    }
  }
  __syncthreads();
  int cntT = min(TILE, E - base);
#pragma unroll
  for (int k = 0; k < TILE / 256; ++k){
    int i = k * 256 + t;
    if (i < cntT){
      int b = sbin[i];
      int pos = gstart[b] + bpreT[b * NBPAD + blk] + (i - lstart[b]);
      tmp[pos] = srec[i];
    }
  }
}

// per bucket: deg hist + local scan -> rp/dinv; LDS scatter -> exact CSR; dump.
__global__ __launch_bounds__(256) void k_build(const unsigned* __restrict__ tmp,
                                               const int* __restrict__ gstart, int nbuck,
                                               int* __restrict__ rp,
                                               float* __restrict__ dinv,
                                               unsigned* __restrict__ col, int N, int E){
  __shared__ unsigned lcol[BCAP];
  __shared__ int deg[512], rpl[512], cur[512];
  __shared__ int ps[256];
  int b = blockIdx.x, t = threadIdx.x;
  int lo = b << BSH;
  int nn = min(512, N - lo);
  int gbase = gstart[b];
  int gend = (b + 1 < nbuck) ? gstart[b + 1] : E;
  int count = gend - gbase;
  for (int i = t; i < 512; i += 256){ deg[i] = 0; cur[i] = 0; }
  __syncthreads();
  const unsigned* trec = tmp + gbase;
  for (int i = t; i < count; i += 256) atomicAdd(&deg[trec[i] >> 17], 1);
  __syncthreads();
  int a0 = deg[2 * t], a1 = deg[2 * t + 1];
  ps[t] = a0 + a1;
  __syncthreads();
  for (int off = 1; off < 256; off <<= 1){
    int v = (t >= off) ? ps[t - off] : 0;
    __syncthreads();
    ps[t] += v;
    __syncthreads();
  }
  int excl = (t == 0) ? 0 : ps[t - 1];
  rpl[2 * t] = excl;
  rpl[2 * t + 1] = excl + a0;
  __syncthreads();
  for (int i = t; i < nn; i += 256){
    rp[lo + i] = gbase + rpl[i];
    dinv[lo + i] = rsqrtf((float)deg[i] + 1.0f);
  }
  if (count <= BCAP){
    for (int i = t; i < count; i += 256){
      unsigned r = trec[i];
      int d = r >> 17;
      int pos = rpl[d] + atomicAdd(&cur[d], 1);
      lcol[pos] = r & 0x1FFFFu;
    }
    __syncthreads();
    for (int i = t; i < count; i += 256) col[gbase + i] = lcol[i];
  } else {                                    // overflow fallback (never expected)
    for (int i = t; i < count; i += 256){
      unsigned r = trec[i];
      int d = r >> 17;
      int pos = rpl[d] + atomicAdd(&cur[d], 1);
      col[gbase + pos] = r & 0x1FFFFu;
    }
  }
}

// ---- weight prep: fp32 -> fp16 (RTN), bias sum -----------------------------
__global__ __launch_bounds__(256) void k_prep_w(const float* __restrict__ Wc,
                                                const float* __restrict__ Wr,
                                                const float* __restrict__ We,
                                                const float* __restrict__ bc,
                                                const float* __restrict__ br,
                                                _Float16* __restrict__ WcF,
                                                _Float16* __restrict__ WrF,
                                                _Float16* __restrict__ WeF,
                                                float* __restrict__ bias_sum){
  int i = blockIdx.x * 256 + threadIdx.x;
  if (i < HD * HD){
    WcF[i] = (_Float16)Wc[i];
    WrF[i] = (_Float16)Wr[i];
    WeF[i] = (_Float16)We[i];
  }
  if (i < HD) bias_sum[i] = bc[i] + br[i];
}

// ---- per-layer aggregation: U[d] = dinv[d] * sum_e X'[src]  (X' pre-scaled)-
// One wave per node. Quarter-wave per edge; lane gathers f16x8 (16B);
// 16 lanes * 16B = 256B row. 4x unroll => 16 gathers in flight per wave.
// Inner loop: 1 gather + 4 pk_add per edge. At the L1-transaction floor.
__global__ __launch_bounds__(256) void k_agg(const _Float16* __restrict__ XsH,
                                             const float* __restrict__ dinv,
                                             const int* __restrict__ rp,
                                             const unsigned* __restrict__ col,
                                             _Float16* __restrict__ U,
                                             int N){
  int w = threadIdx.x >> 6;
  int lane = threadIdx.x & 63;
  int q = lane >> 4;       // edge slot 0..3
  int ql = lane & 15;      // channel group: cols ql*8 .. ql*8+7
  int node = blockIdx.x * 4 + w;
  if (node >= N) return;

  f16x2 acc2[4];
#pragma unroll
  for (int k = 0; k < 4; ++k) acc2[k] = (f16x2)(_Float16)0;

  int b = rp[node], e = rp[node + 1];
  int j = b + q;
  for (; j + 12 < e; j += 16){
    unsigned c0 = col[j];
    unsigned c1 = col[j + 4];
    unsigned c2 = col[j + 8];
    unsigned c3 = col[j + 12];
    f16x8 v0 = ((const f16x8*)(XsH + (size_t)c0 * HD))[ql];
    f16x8 v1 = ((const f16x8*)(XsH + (size_t)c1 * HD))[ql];
    f16x8 v2 = ((const f16x8*)(XsH + (size_t)c2 * HD))[ql];
    f16x8 v3 = ((const f16x8*)(XsH + (size_t)c3 * HD))[ql];
    const f16x2* p0 = (const f16x2*)&v0;
    const f16x2* p1 = (const f16x2*)&v1;
    const f16x2* p2 = (const f16x2*)&v2;
    const f16x2* p3 = (const f16x2*)&v3;
#pragma unroll
    for (int k = 0; k < 4; ++k) acc2[k] += p0[k];
#pragma unroll
    for (int k = 0; k < 4; ++k) acc2[k] += p1[k];
#pragma unroll
    for (int k = 0; k < 4; ++k) acc2[k] += p2[k];
#pragma unroll
    for (int k = 0; k < 4; ++k) acc2[k] += p3[k];
  }
  for (; j < e; j += 4){
    unsigned c0 = col[j];
    f16x8 v0 = ((const f16x8*)(XsH + (size_t)c0 * HD))[ql];
    const f16x2* p0 = (const f16x2*)&v0;
#pragma unroll
    for (int k = 0; k < 4; ++k) acc2[k] += p0[k];
  }

  // f32 finish: cross-quarter reduce + dinv[dst] scale
  float acc[8];
#pragma unroll
  for (int k = 0; k < 4; ++k){
    acc[2 * k]     = (float)acc2[k][0];
    acc[2 * k + 1] = (float)acc2[k][1];
  }
  float dn = dinv[node];
#pragma unroll
  for (int i = 0; i < 8; ++i){
    acc[i] += __shfl_xor(acc[i], 16, 64);
    acc[i] += __shfl_xor(acc[i], 32, 64);
    acc[i] *= dn;
  }
  if (q == 0){
    f16x8 o;
#pragma unroll
    for (int i = 0; i < 8; ++i) o[i] = (_Float16)acc[i];
    ((f16x8*)(U + (size_t)node * HD))[ql] = o;
  }
}

// ---- fused fp16 GEMM, ONE weight matrix staged at a time (32KB LDS) --------
// State array A2h holds X' = dinv*X. Raw operands rebuilt per-row:
//   pass A: a1 = U + ((d^2-1)/d) X'  (pk_fma);  pass B: a2 = (1/d) X' (pk_mul)
// r15: X' cached in registers across passes (pass B does no global loads).
// Output store: X'new = dinv[row] * relu(acc+bias).
// two=false (encoder): a1 = cvt16(x fp32); store scaled.
// decode: skip stores, val[row] = dot(raw out_row, Wd) + bd[0].
__global__ __launch_bounds__(256) void k_gemm(
    const float* __restrict__ A1f,            // encoder input x (fp32) or null
    const _Float16* __restrict__ A1h,         // U (fp16) or null
    const _Float16* A2h,                      // X' (aliases outXsH) or null
    const _Float16* __restrict__ W1,          // WcF or WeF
    const _Float16* __restrict__ W2,          // WrF or null
    const float* __restrict__ dinvp,
    const float* __restrict__ bias,
    _Float16* outXsH,
    const float* __restrict__ Wd, const float* __restrict__ bd,
    float* __restrict__ val,
    int N, int relu, int decode){
  __shared__ _Float16 wsm[HD * HD];           // 32KB: [row][slot^]
  f16x8* smv = (f16x8*)wsm;
  int t = threadIdx.x;

  {
    const f16x8* g1 = (const f16x8*)W1;
    for (int i = t; i < HD * HD / 8; i += 256){
      int row = i >> 4, slot = i & 15;
      smv[(row << 4) | (slot ^ (row & 7))] = g1[i];
    }
  }
  __syncthreads();

  int wid = blockIdx.x * 4 + (t >> 6);
  int row0 = wid * 32;
  bool act = (row0 < N);
  int rowb = act ? row0 : 0;
  int lane = t & 63;
  int r = lane & 15;
  int kg = lane >> 4;

  f32x4 acc[2][8];
#pragma unroll
  for (int s = 0; s < 2; ++s)
#pragma unroll
    for (int c = 0; c < 8; ++c) acc[s][c] = (f32x4)0.0f;

  const bool two = (A2h != nullptr);
  f16x2 srA2[2], srB2[2];
  if (two){
#pragma unroll
    for (int s = 0; s < 2; ++s){
      float d = dinvp[rowb + s * 16 + r];
      float rd = 1.0f / d;
      _Float16 ha = (_Float16)((d * d - 1.0f) * rd);
      _Float16 hb = (_Float16)rd;
      srA2[s][0] = ha; srA2[s][1] = ha;
      srB2[s][0] = hb; srB2[s][1] = hb;
    }
  }

  f16x8 xcache[4][2];                          // X' register cache (32 VGPR)

  // ---- pass A ----
#pragma unroll
  for (int kst = 0; kst < 4; ++kst){
    int k0 = kst * 32 + kg * 8;
    f16x8 a1[2];
#pragma unroll
    for (int s = 0; s < 2; ++s){
      size_t ao = (size_t)(rowb + s * 16 + r) * HD + k0;
      if (two){
        f16x8 uh = *(const f16x8*)(A1h + ao);
        f16x8 xv = *(const f16x8*)(A2h + ao);
        xcache[kst][s] = xv;
        f16x2* a1p = (f16x2*)&a1[s];
        const f16x2* up = (const f16x2*)&uh;
        const f16x2* xp = (const f16x2*)&xv;
#pragma unroll
        for (int k = 0; k < 4; ++k) a1p[k] = up[k] + srA2[s] * xp[k];
      } else {
        f32x8 u = *(const f32x8*)(A1f + ao);
#pragma unroll
        for (int i = 0; i < 8; ++i) a1[s][i] = (_Float16)u[i];
      }
    }
    int swz = (kst * 4 + kg) ^ (r & 7);
#pragma unroll
    for (int ct = 0; ct < 8; ++ct){
      f16x8 b1 = smv[((ct * 16 + r) << 4) | swz];
#pragma unroll
      for (int s = 0; s < 2; ++s)
        acc[s][ct] = __builtin_amdgcn_mfma_f32_16x16x32_f16(a1[s], b1, acc[s][ct], 0, 0, 0);
    }
  }

  // ---- pass B (no global loads: X' from registers) ----
  if (two){
    __syncthreads();
    const f16x8* g2 = (const f16x8*)W2;
    for (int i = t; i < HD * HD / 8; i += 256){
      int row = i >> 4, slot = i & 15;
      smv[(row << 4) | (slot ^ (row & 7))] = g2[i];
    }
    __syncthreads();
#pragma unroll
    for (int kst = 0; kst < 4; ++kst){
      f16x8 a2[2];
#pragma unroll
      for (int s = 0; s < 2; ++s){
        f16x2* a2p = (f16x2*)&a2[s];
        const f16x2* xp = (const f16x2*)&xcache[kst][s];
#pragma unroll
        for (int k = 0; k < 4; ++k) a2p[k] = srB2[s] * xp[k];
      }
      int swz = (kst * 4 + kg) ^ (r & 7);
#pragma unroll
      for (int ct = 0; ct < 8; ++ct){
        f16x8 b2 = smv[((ct * 16 + r) << 4) | swz];
#pragma unroll
        for (int s = 0; s < 2; ++s)
          acc[s][ct] = __builtin_amdgcn_mfma_f32_16x16x32_f16(a2[s], b2, acc[s][ct], 0, 0, 0);
      }
    }
  }

  // epilogue: C/D layout col = lane&15, row = kg*4 + reg
  float dout[2][4];
  if (act && !decode){
#pragma unroll
    for (int s = 0; s < 2; ++s)
#pragma unroll
      for (int j = 0; j < 4; ++j)
        dout[s][j] = dinvp[row0 + s * 16 + kg * 4 + j];
  }
  float rowp[2][4] = {{0.f,0.f,0.f,0.f},{0.f,0.f,0.f,0.f}};
#pragma unroll
  for (int s = 0; s < 2; ++s){
#pragma unroll
    for (int ct = 0; ct < 8; ++ct){
      int cc = ct * 16 + r;
      float bv = bias[cc];
      float wdv = decode ? Wd[cc] : 0.f;
#pragma unroll
      for (int j = 0; j < 4; ++j){
        float v = acc[s][ct][j] + bv;
        if (relu) v = fmaxf(v, 0.0f);
        if (decode){
          rowp[s][j] += v * wdv;
        } else if (act){
          int rr = row0 + s * 16 + kg * 4 + j;
          outXsH[(size_t)rr * HD + cc] = (_Float16)(dout[s][j] * v);
        }
      }
    }
  }
  if (decode && act){
    float bd0 = bd[0];
#pragma unroll
    for (int s = 0; s < 2; ++s)
#pragma unroll
      for (int j = 0; j < 4; ++j){
        float tt = rowp[s][j];
        tt += __shfl_xor(tt, 1, 64);
        tt += __shfl_xor(tt, 2, 64);
        tt += __shfl_xor(tt, 4, 64);
        tt += __shfl_xor(tt, 8, 64);
        if (r == 0) val[row0 + s * 16 + kg * 4 + j] = tt + bd0;
      }
  }
}

// ---- pooling: LDS histogram per block, few global atomics ------------------
#define POOL_CHUNK 1024
__global__ __launch_bounds__(256) void k_pool(const float* __restrict__ val,
                                              const int* __restrict__ batch,
                                              float* __restrict__ out, int N, int G){
  __shared__ float acc[4096];
  int t = threadIdx.x;
  int lo = blockIdx.x * POOL_CHUNK;
  int hi = min(lo + POOL_CHUNK, N);
  if (G <= 4096){
    for (int i = t; i < G; i += 256) acc[i] = 0.f;
    __syncthreads();
    for (int i = lo + t; i < hi; i += 256) atomicAdd(&acc[batch[i]], val[i]);
    __syncthreads();
    for (int i = t; i < G; i += 256){
      float v = acc[i];
      if (v != 0.f) atomicAdd(&out[i], v);
    }
  } else {
    for (int i = lo + t; i < hi; i += 256) atomicAdd(&out[batch[i]], val[i]);
  }
}

// ---- launcher ---------------------------------------------------------------
extern "C" void kernel_launch(void* const* d_in, const int* in_sizes, int n_in,
                              void* d_out, int out_size, void* d_ws, size_t ws_size,
                              hipStream_t stream){
  const float* x      = (const float*)d_in[0];
  const int*   ei     = (const int*)d_in[1];
  const int*   batch  = (const int*)d_in[2];
  const float* W_enc  = (const float*)d_in[3];
  const float* b_enc  = (const float*)d_in[4];
  const float* W_conv = (const float*)d_in[5];
  const float* b_conv = (const float*)d_in[6];
  const float* W_res  = (const float*)d_in[7];
  const float* b_res  = (const float*)d_in[8];
  const float* W_dec  = (const float*)d_in[9];
  const float* b_dec  = (const float*)d_in[10];

  const int N = in_sizes[0] / HD;
  const int E = in_sizes[1] / 2;
  const int NB = (E + TILE - 1) / TILE;            // <= NBPAD
  const int nbuck = (N + (1 << BSH) - 1) >> BSH;   // <= 256
  float* out = (float*)d_out;

  char* ws = (char*)d_ws;
  size_t off = 0;
  auto alloc = [&](size_t bytes) -> char* {
    char* p = ws + off;
    off += (bytes + 255) & ~(size_t)255;
    return p;
  };
  int*   rp    = (int*)  alloc(((size_t)N + 1) * 4);
  float* dinv  = (float*)alloc((size_t)N * 4);
  int*   bcnt  = (int*)  alloc((size_t)NBPAD * 256 * 4);
  int*   bpreT = (int*)  alloc((size_t)256 * NBPAD * 4);
  int*   btot  = (int*)  alloc(256 * 4);
  int*   gstart= (int*)  alloc(256 * 4);
  unsigned* tmp= (unsigned*)alloc((size_t)E * 4);
  unsigned* col= (unsigned*)alloc((size_t)E * 4);
  _Float16* XsH= (_Float16*)alloc((size_t)N * HD * 2);
  _Float16* U  = (_Float16*)alloc((size_t)N * HD * 2);
  float* val   = (float*)alloc((size_t)N * 4);
  _Float16* WcF = (_Float16*)alloc((size_t)HD * HD * 2);
  _Float16* WrF = (_Float16*)alloc((size_t)HD * HD * 2);
  _Float16* WeF = (_Float16*)alloc((size_t)HD * HD * 2);
  float* bias_sum = (float*)alloc((size_t)HD * 4);

  hipMemsetAsync(out, 0, (size_t)out_size * 4, stream);

  const int* src = ei;
  const int* dst = ei + E;

  k_count  <<<NB, 256, 0, stream>>>(dst, E, bcnt);
  k_btot   <<<nbuck, 256, 0, stream>>>(bcnt, bpreT, btot, NB);
  k_gscan  <<<1, 256, 0, stream>>>(btot, gstart, nbuck, rp, N, E);
  k_scatter<<<NB, 256, 0, stream>>>(src, dst, E, bpreT, gstart, tmp);
  k_build  <<<nbuck, 256, 0, stream>>>(tmp, gstart, nbuck, rp, dinv, col, N, E);
  k_prep_w <<<(HD * HD + 255) / 256, 256, 0, stream>>>(W_conv, W_res, W_enc, b_conv, b_res,
                                                       WcF, WrF, WeF, bias_sum);

  int gemm_blocks = ((N + 31) / 32 + 3) / 4;
  int node_blocks = (N + 3) / 4;

  // encoder: XsH = dinv * fp16(x @ W_enc^T + b_enc)   (pre-scaled state)
  k_gemm<<<gemm_blocks, 256, 0, stream>>>(x, nullptr, nullptr, WeF, nullptr,
                                          dinv, b_enc, XsH,
                                          nullptr, nullptr, nullptr, N, 0, 0);

  for (int l = 0; l < 5; ++l){
    k_agg<<<node_blocks, 256, 0, stream>>>(XsH, dinv, rp, col, U, N);
    int last = (l == 4);
    k_gemm<<<gemm_blocks, 256, 0, stream>>>(nullptr, U, XsH, WcF, WrF,
                                            dinv, bias_sum, XsH,
                                            W_dec, b_dec, val, N, 1, last);
  }

  k_pool<<<(N + POOL_CHUNK - 1) / POOL_CHUNK, 256, 0, stream>>>(val, batch, out, N, out_size);
}